// Round 5
// baseline (488.562 us; speedup 1.0000x reference)
//
#include <hip/hip_runtime.h>
#include <cstdint>

#define NB 32
#define NNODES 1024
#define DD 256
#define KNB 64
#define MTOT (NB * NNODES)  // 32768

// Scaling: activations stored as split(64*a), weights as split(1024*w).
// acc = sum (64a)(1024w) = 65536 * a.w  -> epilogue * 1/65536.
// scores acc = (64q).(64k) = 4096 q.k -> q.k/16 = acc/65536 too.
#define INV65536 1.52587890625e-05f

typedef _Float16 half8 __attribute__((ext_vector_type(8)));
typedef _Float16 half4 __attribute__((ext_vector_type(4)));
typedef float f32x4 __attribute__((ext_vector_type(4)));

typedef __attribute__((address_space(3))) uint32_t lds_u32;
typedef __attribute__((address_space(1))) uint32_t glb_u32;

// 16B async global->LDS. LDS dest wave-uniform; HW adds lane*16.
__device__ __forceinline__ void gll16(const _Float16* g, _Float16* l) {
  __builtin_amdgcn_global_load_lds((const glb_u32*)g, (lds_u32*)l, 16, 0, 0);
}

__device__ __forceinline__ void split2(float v, _Float16& h, _Float16& l) {
  h = (_Float16)v;
  l = (_Float16)(v - (float)h);
}

__device__ __forceinline__ uint32_t pack2(float v) {
  _Float16 h, l;
  split2(v, h, l);
  return (uint32_t)__builtin_bit_cast(uint16_t, h) |
         ((uint32_t)__builtin_bit_cast(uint16_t, l) << 16);
}

// =====================================================================
// prep_w: W[k][n] fp32 -> W_T[n][k] fp16x2, scaled by 1024.
// =====================================================================
__global__ __launch_bounds__(256) void prep_w(const float* __restrict__ wq,
                                              const float* __restrict__ wk,
                                              const float* __restrict__ wv,
                                              const float* __restrict__ w1,
                                              const float* __restrict__ w2,
                                              _Float16* __restrict__ WT) {
  const int idx = blockIdx.x * 256 + threadIdx.x;  // < 5*65536
  const int wsel = idx >> 16;
  const int rem = idx & 65535;
  const int k = rem >> 8, n = rem & 255;
  const float* src = (wsel == 0) ? wq : (wsel == 1) ? wk : (wsel == 2) ? wv : (wsel == 3) ? w1 : w2;
  const float v = src[rem] * 1024.0f;
  _Float16 h1, h2;
  split2(v, h1, h2);
  WT[(size_t)wsel * 131072 + n * 256 + k] = h1;
  WT[(size_t)wsel * 131072 + 65536 + n * 256 + k] = h2;
}

// LDS tile layout: [128 rows][8 chunks of 8 halfs], chunk XOR-swizzled by (row&7)
#define SWZ_OFF(r, cc) ((r) * 64 + (((cc) ^ ((r)&7)) << 3))

// =====================================================================
// gemm_qkv v5: A = x fp32 (split *64 on the fly, LDS-staged),
// B = W_T splits loaded DIRECT global->VGPR (L2-resident, no LDS).
// LDS 32KB (A only) -> better occupancy. Epilogue: per-wave LDS
// transpose -> 128B-contiguous per-lane stores (no write amplification).
// Grid 1D 1536, XCD-swizzled: 6 sibling blocks (same m-rows) per XCD.
// =====================================================================
__global__ __launch_bounds__(256) void gemm_qkv(const float* __restrict__ x,
                                                const _Float16* __restrict__ WT,
                                                const float* __restrict__ bq,
                                                const float* __restrict__ bk,
                                                const float* __restrict__ bv,
                                                _Float16* __restrict__ Q1, _Float16* __restrict__ Q2,
                                                _Float16* __restrict__ K1, _Float16* __restrict__ K2,
                                                float* __restrict__ V) {
  __shared__ _Float16 sm[2 * 8192];  // A1,A2 tiles [128][64], 16KB each
  _Float16* sA1 = sm;
  _Float16* sA2 = sm + 8192;

  const int tid = threadIdx.x;
  const int lane = tid & 63, w = tid >> 6;
  const int r16 = lane & 15, kg = lane >> 4;
  const int wm = (w >> 1) * 64, wn = (w & 1) * 64;

  // XCD swizzle: id%8 = XCD; 6 siblings (j=0..5) of each m-tile share id%8
  const int id = blockIdx.x;
  const int c8 = id & 7, t = id >> 3;   // t in 0..191
  const int gy = (t / 6) * 8 + c8;      // m-tile 0..255
  const int j6 = t % 6;
  const int wsel = j6 >> 1;
  const int n0 = (j6 & 1) * 128;
  const int m0 = gy * 128;

  const _Float16* B1 = WT + (size_t)wsel * 131072;
  const _Float16* B2 = B1 + 65536;

  const int ra = tid >> 1, hh = tid & 1;

  f32x4 acc[4][4];
#pragma unroll
  for (int i = 0; i < 4; ++i)
#pragma unroll
    for (int j = 0; j < 4; ++j) acc[i][j] = f32x4{0.f, 0.f, 0.f, 0.f};

  for (int k0 = 0; k0 < DD; k0 += 64) {
    const float* xr = x + (size_t)(m0 + ra) * DD + k0 + hh * 32;
    float4 xv[8];
#pragma unroll
    for (int i = 0; i < 8; ++i) xv[i] = *(const float4*)(xr + i * 4);

    __syncthreads();  // previous compute done; LDS free

    // A tile: split (64*x) -> fp16x2, swizzled ds_write (rotated chunk order)
#pragma unroll
    for (int qq = 0; qq < 4; ++qq) {
      const int q = (qq + (tid & 3)) & 3;
      const float4 u0 = xv[q * 2], u1 = xv[q * 2 + 1];
      const float vals[8] = {u0.x, u0.y, u0.z, u0.w, u1.x, u1.y, u1.z, u1.w};
      half8 hi, lo;
#pragma unroll
      for (int e = 0; e < 8; ++e) {
        _Float16 a, b;
        split2(vals[e] * 64.0f, a, b);
        hi[e] = a;
        lo[e] = b;
      }
      const int off = SWZ_OFF(ra, hh * 4 + q);
      *(half8*)(sA1 + off) = hi;
      *(half8*)(sA2 + off) = lo;
    }
    __syncthreads();

#pragma unroll
    for (int s = 0; s < 2; ++s) {
      // B frags direct from global (L2-resident weights)
      half8 bA[4], bB[4];
#pragma unroll
      for (int nj = 0; nj < 4; ++nj) {
        const size_t bo = (size_t)(n0 + wn + nj * 16 + r16) * DD + k0 + ((s * 4 + kg) << 3);
        bA[nj] = *(const half8*)(B1 + bo);
        bB[nj] = *(const half8*)(B2 + bo);
      }
      half8 aA[4], aB[4];
#pragma unroll
      for (int mi = 0; mi < 4; ++mi) {
        const int off = SWZ_OFF(wm + mi * 16 + r16, s * 4 + kg);
        aA[mi] = *(const half8*)(sA1 + off);
        aB[mi] = *(const half8*)(sA2 + off);
      }
#pragma unroll
      for (int mi = 0; mi < 4; ++mi)
#pragma unroll
        for (int nj = 0; nj < 4; ++nj) {
          acc[mi][nj] = __builtin_amdgcn_mfma_f32_16x16x32_f16(aA[mi], bA[nj], acc[mi][nj], 0, 0, 0);
          acc[mi][nj] = __builtin_amdgcn_mfma_f32_16x16x32_f16(aA[mi], bB[nj], acc[mi][nj], 0, 0, 0);
          acc[mi][nj] = __builtin_amdgcn_mfma_f32_16x16x32_f16(aB[mi], bA[nj], acc[mi][nj], 0, 0, 0);
        }
    }
  }

  // ---- epilogue: per-wave LDS transpose -> coalesced 128B/lane stores ----
  __syncthreads();  // all waves done reading A tiles
  uint32_t* Uw = reinterpret_cast<uint32_t*>(sm) + (w << 11);  // 2048 uints/wave

  const float* bsel = (wsel == 0) ? bq : (wsel == 1) ? bk : bv;
  float biasv[4];
#pragma unroll
  for (int nj = 0; nj < 4; ++nj) biasv[nj] = bsel[n0 + wn + nj * 16 + r16];

  const int row = m0 + wm + lane;
  uint2 o1[16], o2[16];  // part1/part2 packed halfs, [h*8 + c4]

#pragma unroll
  for (int h = 0; h < 2; ++h) {
    // write phase: 64 rows x 32 cols (nj = 2h, 2h+1), XOR-swizzled
#pragma unroll
    for (int njh = 0; njh < 2; ++njh) {
      const int nj = 2 * h + njh;
#pragma unroll
      for (int mi = 0; mi < 4; ++mi)
#pragma unroll
        for (int j = 0; j < 4; ++j) {
          const int rl = mi * 16 + kg * 4 + j;
          const int cl = njh * 16 + r16;
          const int addr = rl * 32 + ((((cl >> 2) ^ (rl & 7)) << 2) | (cl & 3));
          uint32_t val;
          if (wsel == 2) {
            val = __float_as_uint(acc[mi][nj][j] * INV65536 + biasv[nj]);
          } else {
            val = pack2(acc[mi][nj][j] * (1.0f / 1024.0f) + 64.0f * biasv[nj]);
          }
          Uw[addr] = val;
        }
    }
    asm volatile("s_waitcnt lgkmcnt(0)" ::: "memory");
    // read phase: lane = local row; 32 cols contiguous
#pragma unroll
    for (int c4 = 0; c4 < 8; ++c4) {
      uint4 u;
      const uint32_t* p = &Uw[lane * 32 + ((c4 ^ (lane & 7)) << 2)];
      u.x = p[0]; u.y = p[1]; u.z = p[2]; u.w = p[3];
      if (wsel == 2) {
        *(uint4*)(V + (size_t)row * DD + n0 + wn + h * 32 + c4 * 4) = u;
      } else {
        uint2 a, b;
        a.x = (u.x & 0xffffu) | (u.y << 16);
        a.y = (u.z & 0xffffu) | (u.w << 16);
        b.x = (u.x >> 16) | (u.y & 0xffff0000u);
        b.y = (u.z >> 16) | (u.w & 0xffff0000u);
        o1[h * 8 + c4] = a;
        o2[h * 8 + c4] = b;
      }
    }
    __syncthreads();  // wave regions are private, but keep passes aligned (cheap)
  }

  if (wsel != 2) {
    _Float16* P1 = (wsel == 0) ? Q1 : K1;
    _Float16* P2 = (wsel == 0) ? Q2 : K2;
    char* p1 = (char*)(P1 + (size_t)row * DD + n0 + wn);
    char* p2 = (char*)(P2 + (size_t)row * DD + n0 + wn);
    const uint4* s1 = (const uint4*)o1;
    const uint4* s2 = (const uint4*)o2;
#pragma unroll
    for (int q = 0; q < 8; ++q) {
      *(uint4*)(p1 + q * 16) = s1[q];
      *(uint4*)(p2 + q * 16) = s2[q];
    }
  }
}

// =====================================================================
// gemm_split<EPI>: A,B pre-split fp16x2, K-major rows (NT).
// EPI 0: C = acc/65536 + bias          (w1 -> H fp32), grid (2,256)
// EPI 1: C = acc/65536 + bias + resid  (w2 -> out fp32), grid (2,256)
// EPI 2: S = acc/65536 + adj           (scores), grid 1D 2048 XCD-swizzled,
//        LDS-transpose epilogue (256B/lane S writes, coalesced adj reads)
// =====================================================================
template <int EPI>
__global__ __launch_bounds__(256) void gemm_split(const _Float16* __restrict__ A1,
                                                  const _Float16* __restrict__ A2,
                                                  const _Float16* __restrict__ B1g,
                                                  const _Float16* __restrict__ B2g,
                                                  const float* __restrict__ bias,
                                                  const float* __restrict__ resid,
                                                  float* __restrict__ C) {
  __shared__ _Float16 sm[4 * 8192];
  _Float16* sA1 = sm;
  _Float16* sA2 = sm + 8192;
  _Float16* sB1 = sm + 16384;
  _Float16* sB2 = sm + 24576;

  const int tid = threadIdx.x;
  const int lane = tid & 63, w = tid >> 6;
  const int r16 = lane & 15, kg = lane >> 4;
  const int rsub = lane >> 3, csub = lane & 7;
  const int wm = (w >> 1) * 64, wn = (w & 1) * 64;

  int n0, m0;
  if (EPI == 2) {
    // XCD swizzle: co-locate all 64 blocks of one batch b on one XCD
    const int id = blockIdx.x;
    const int c8 = id & 7, t = id >> 3;          // t in 0..255
    const int Bb = ((t >> 6) << 3) + c8;         // batch 0..31
    const int r = (t >> 3) & 7;
    const int bx = t & 7;
    n0 = bx * 128;
    m0 = (Bb * 8 + r) * 128;
  } else {
    n0 = blockIdx.x * 128;
    m0 = blockIdx.y * 128;
  }

  const _Float16* pB1 = B1g;
  const _Float16* pB2 = B2g;
  if (EPI == 2) {
    const size_t boff = (size_t)(m0 >> 10) * NNODES * DD;
    pB1 += boff;
    pB2 += boff;
  }

  f32x4 acc[4][4];
#pragma unroll
  for (int i = 0; i < 4; ++i)
#pragma unroll
    for (int j = 0; j < 4; ++j) acc[i][j] = f32x4{0.f, 0.f, 0.f, 0.f};

  for (int k0 = 0; k0 < DD; k0 += 64) {
    __syncthreads();
#pragma unroll
    for (int it = 0; it < 4; ++it) {
      const int r = (w << 5) + (it << 3) + rsub;
      const int swz = ((csub ^ (r & 7)) << 3);
      const int ldso = (w << 11) + (it << 9);
      gll16(A1 + (size_t)(m0 + r) * DD + k0 + swz, sA1 + ldso);
      gll16(A2 + (size_t)(m0 + r) * DD + k0 + swz, sA2 + ldso);
      gll16(pB1 + (size_t)(n0 + r) * DD + k0 + swz, sB1 + ldso);
      gll16(pB2 + (size_t)(n0 + r) * DD + k0 + swz, sB2 + ldso);
    }
    __syncthreads();

#pragma unroll
    for (int s = 0; s < 2; ++s) {
      half8 aA[4], aB[4], bA[4], bB[4];
#pragma unroll
      for (int mi = 0; mi < 4; ++mi) {
        const int off = SWZ_OFF(wm + mi * 16 + r16, s * 4 + kg);
        aA[mi] = *(const half8*)(sA1 + off);
        aB[mi] = *(const half8*)(sA2 + off);
      }
#pragma unroll
      for (int nj = 0; nj < 4; ++nj) {
        const int off = SWZ_OFF(wn + nj * 16 + r16, s * 4 + kg);
        bA[nj] = *(const half8*)(sB1 + off);
        bB[nj] = *(const half8*)(sB2 + off);
      }
#pragma unroll
      for (int mi = 0; mi < 4; ++mi)
#pragma unroll
        for (int nj = 0; nj < 4; ++nj) {
          acc[mi][nj] = __builtin_amdgcn_mfma_f32_16x16x32_f16(aA[mi], bA[nj], acc[mi][nj], 0, 0, 0);
          acc[mi][nj] = __builtin_amdgcn_mfma_f32_16x16x32_f16(aA[mi], bB[nj], acc[mi][nj], 0, 0, 0);
          acc[mi][nj] = __builtin_amdgcn_mfma_f32_16x16x32_f16(aB[mi], bA[nj], acc[mi][nj], 0, 0, 0);
        }
    }
  }

  if (EPI == 2) {
    // full-tile LDS transpose epilogue: 16KB/wave (64KB total, reuses staging)
    __syncthreads();
    uint32_t* Uw = reinterpret_cast<uint32_t*>(sm) + (w << 12);  // 4096 uints/wave
#pragma unroll
    for (int nj = 0; nj < 4; ++nj)
#pragma unroll
      for (int mi = 0; mi < 4; ++mi)
#pragma unroll
        for (int j = 0; j < 4; ++j) {
          const int rl = mi * 16 + kg * 4 + j;
          const int cl = nj * 16 + r16;
          const int addr = rl * 64 + ((((cl >> 2) ^ (rl & 15)) << 2) | (cl & 3));
          Uw[addr] = __float_as_uint(acc[mi][nj][j] * INV65536);
        }
    asm volatile("s_waitcnt lgkmcnt(0)" ::: "memory");
    const int row = m0 + wm + lane;
    const float* adjrow = bias + (size_t)(row & (NNODES - 1)) * NNODES + n0 + wn;
    float* srow = C + (size_t)row * NNODES + n0 + wn;
#pragma unroll
    for (int c4 = 0; c4 < 16; ++c4) {
      const uint32_t* p = &Uw[lane * 64 + ((c4 ^ (lane & 15)) << 2)];
      const float4 ad = *(const float4*)(adjrow + c4 * 4);
      float4 o;
      o.x = __uint_as_float(p[0]) + ad.x;
      o.y = __uint_as_float(p[1]) + ad.y;
      o.z = __uint_as_float(p[2]) + ad.z;
      o.w = __uint_as_float(p[3]) + ad.w;
      *(float4*)(srow + c4 * 4) = o;
    }
  } else {
#pragma unroll
    for (int mi = 0; mi < 4; ++mi)
#pragma unroll
      for (int nj = 0; nj < 4; ++nj) {
        const int col = n0 + wn + nj * 16 + r16;
#pragma unroll
        for (int j = 0; j < 4; ++j) {
          const int rr = m0 + wm + mi * 16 + kg * 4 + j;
          const float v = acc[mi][nj][j] * INV65536;
          if (EPI == 0) {
            C[(size_t)rr * DD + col] = v + bias[col];
          } else {
            C[(size_t)rr * DD + col] = v + bias[col] + resid[(size_t)rr * DD + col];
          }
        }
      }
  }
}

// =====================================================================
// Top-64 + masked softmax (in-place) + sparse messages. One wave/row.
// 21-bit fixed-point radix keys counted via ballot+popcount; candidates
// near the boundary get exact fp32 recompute (jax tie semantics).
// =====================================================================
__global__ __launch_bounds__(256) void topk_softmax_msg(float* __restrict__ S,
                                                        const float* __restrict__ V,
                                                        const _Float16* __restrict__ Q1,
                                                        const _Float16* __restrict__ Q2,
                                                        const _Float16* __restrict__ K1,
                                                        const _Float16* __restrict__ K2,
                                                        const float* __restrict__ adj,
                                                        _Float16* __restrict__ M1,
                                                        _Float16* __restrict__ M2) {
  const int tid = threadIdx.x;
  const int w = tid >> 6, lane = tid & 63;
  const int row = blockIdx.x * 4 + w;
  const int b = row >> 10;
  const int m = row & (NNODES - 1);
  float* Srow = S + (size_t)row * NNODES;

  __shared__ float2 spair[4][KNB];  // (wgt, idx bits)
  __shared__ int cidxs[4][32];
  __shared__ float cex[4][32];
  __shared__ int csel[4][32];

  if (lane < KNB) spair[w][lane] = make_float2(0.0f, __int_as_float(0));

  float s[16];
#pragma unroll
  for (int c = 0; c < 4; ++c) {
    const float4 sv = *(const float4*)(Srow + c * 256 + lane * 4);
    s[c * 4 + 0] = sv.x;
    s[c * 4 + 1] = sv.y;
    s[c * 4 + 2] = sv.z;
    s[c * 4 + 3] = sv.w;
  }

  unsigned key[16];
#pragma unroll
  for (int t = 0; t < 16; ++t) {
    const float f = fminf(fmaxf((s[t] + 8.0f) * 131072.0f, 0.0f), 2097151.0f);
    key[t] = (unsigned)f;
  }

  unsigned cur = 0u;
#pragma unroll 1
  for (int bit = 20; bit >= 0; --bit) {
    const unsigned cand = cur | (1u << bit);
    int cnt = 0;
#pragma unroll
    for (int t = 0; t < 16; ++t) cnt += (int)__popcll(__ballot(key[t] >= cand));
    if (cnt >= KNB) cur = cand;
  }

  const float s64f = (float)cur * (16.0f / 2097152.0f) - 8.0f;
  const float thrHi = s64f + 6e-5f;
  const float thrLo = s64f - 5e-5f;

  const unsigned long long ltmask = (1ull << lane) - 1ull;
  unsigned hm = 0u, cm = 0u;
  int cpos[16];
  int nhi = 0, ncand = 0;
#pragma unroll
  for (int c = 0; c < 4; ++c) {
    bool hiv[4], cdv[4];
    unsigned long long mh[4], mc[4];
#pragma unroll
    for (int e = 0; e < 4; ++e) {
      const int t = c * 4 + e;
      hiv[e] = (s[t] > thrHi);
      cdv[e] = (!hiv[e]) && (s[t] >= thrLo);
      mh[e] = __ballot(hiv[e]);
      mc[e] = __ballot(cdv[e]);
    }
    const int below = (int)__popcll(mc[0] & ltmask) + (int)__popcll(mc[1] & ltmask) +
                      (int)__popcll(mc[2] & ltmask) + (int)__popcll(mc[3] & ltmask);
    int own = 0;
#pragma unroll
    for (int e = 0; e < 4; ++e) {
      const int t = c * 4 + e;
      cpos[t] = -1;
      if (hiv[e]) hm |= (1u << t);
      if (cdv[e]) {
        cm |= (1u << t);
        const int p = ncand + below + own;
        cpos[t] = p;
        if (p < 32) cidxs[w][p] = c * 256 + lane * 4 + e;
        ++own;
      }
    }
    nhi += (int)__popcll(mh[0]) + (int)__popcll(mh[1]) + (int)__popcll(mh[2]) + (int)__popcll(mh[3]);
    ncand += (int)__popcll(mc[0]) + (int)__popcll(mc[1]) + (int)__popcll(mc[2]) + (int)__popcll(mc[3]);
  }
  const int need = KNB - nhi;

  unsigned selm;
  if (ncand == need) {
    selm = hm | cm;
  } else {
    const int nc = (ncand <= 32) ? ncand : 32;
    const int nd = (need <= nc) ? need : nc;
    const size_t qoff = (size_t)row * DD + lane * 4;
    const half4 q1v = *(const half4*)(Q1 + qoff);
    const half4 q2v = *(const half4*)(Q2 + qoff);
    float qf[4];
#pragma unroll
    for (int e = 0; e < 4; ++e) qf[e] = (float)q1v[e] + (float)q2v[e];
    const float* adjrow = adj + (size_t)m * NNODES;
#pragma unroll 1
    for (int t2 = 0; t2 < nc; ++t2) {
      const int j = cidxs[w][t2];
      const size_t koff = ((size_t)b * NNODES + j) * DD + lane * 4;
      const half4 k1v = *(const half4*)(K1 + koff);
      const half4 k2v = *(const half4*)(K2 + koff);
      float part = 0.0f;
#pragma unroll
      for (int e = 0; e < 4; ++e) part = fmaf(qf[e], (float)k1v[e] + (float)k2v[e], part);
#pragma unroll
      for (int off = 32; off > 0; off >>= 1) part += __shfl_xor(part, off);
      if (lane == 0) cex[w][t2] = part * INV65536 + adjrow[j];
    }
    if (lane < nc) {
      const float et = cex[w][lane];
      int rank = 0;
      for (int u = 0; u < nc; ++u) {
        const float eu = cex[w][u];
        rank += (eu > et || (eu == et && u < lane)) ? 1 : 0;
      }
      csel[w][lane] = (rank < nd) ? 1 : 0;
    }
    selm = hm;
#pragma unroll
    for (int t = 0; t < 16; ++t) {
      if (((cm >> t) & 1u) && cpos[t] >= 0 && cpos[t] < 32 && csel[w][cpos[t]]) selm |= (1u << t);
    }
  }

  float rmax = s[0];
#pragma unroll
  for (int t = 1; t < 16; ++t) rmax = fmaxf(rmax, s[t]);
#pragma unroll
  for (int off = 32; off > 0; off >>= 1) rmax = fmaxf(rmax, __shfl_xor(rmax, off));

  float p[16];
  float sum = 0.0f;
#pragma unroll
  for (int t = 0; t < 16; ++t) {
    p[t] = __expf(s[t] - rmax);
    if ((selm >> t) & 1u) sum += p[t];
  }
#pragma unroll
  for (int off = 32; off > 0; off >>= 1) sum += __shfl_xor(sum, off);
  const float inv = 1.0f / sum;

  int run = 0;
#pragma unroll
  for (int c = 0; c < 4; ++c) {
    bool sel4[4];
    unsigned long long ms[4];
#pragma unroll
    for (int e = 0; e < 4; ++e) {
      sel4[e] = (selm >> (c * 4 + e)) & 1u;
      ms[e] = __ballot(sel4[e]);
    }
    const int below = (int)__popcll(ms[0] & ltmask) + (int)__popcll(ms[1] & ltmask) +
                      (int)__popcll(ms[2] & ltmask) + (int)__popcll(ms[3] & ltmask);
    float4 ow;
    float* owp = (float*)&ow;
    int own = 0;
#pragma unroll
    for (int e = 0; e < 4; ++e) {
      const int t = c * 4 + e;
      const float aw = sel4[e] ? p[t] * inv : 0.0f;
      owp[e] = aw;
      if (sel4[e]) {
        const int pos = run + below + own;
        if (pos < KNB) spair[w][pos] = make_float2(aw, __int_as_float(c * 256 + lane * 4 + e));
        ++own;
      }
    }
    *(float4*)(Srow + c * 256 + lane * 4) = ow;
    run += (int)__popcll(ms[0]) + (int)__popcll(ms[1]) + (int)__popcll(ms[2]) + (int)__popcll(ms[3]);
  }

  const float* Vb = V + (size_t)b * NNODES * DD;
  float4 acc = {0.0f, 0.0f, 0.0f, 0.0f};
#pragma unroll 2
  for (int t = 0; t < KNB; ++t) {
    const float2 pr = spair[w][t];
    const int j = __float_as_int(pr.y);
    const float4 vv = *(const float4*)(Vb + (size_t)j * DD + lane * 4);
    acc.x = fmaf(pr.x, vv.x, acc.x);
    acc.y = fmaf(pr.x, vv.y, acc.y);
    acc.z = fmaf(pr.x, vv.z, acc.z);
    acc.w = fmaf(pr.x, vv.w, acc.w);
  }
  const float av[4] = {acc.x, acc.y, acc.z, acc.w};
  half4 m1, m2;
#pragma unroll
  for (int d = 0; d < 4; ++d) {
    _Float16 a, bb;
    split2(av[d] * 64.0f, a, bb);
    m1[d] = a;
    m2[d] = bb;
  }
  *(half4*)(M1 + (size_t)row * DD + lane * 4) = m1;
  *(half4*)(M2 + (size_t)row * DD + lane * 4) = m2;
}

// =====================================================================
// LayerNorm + ReLU: H fp32 -> split(64*y).
// =====================================================================
__global__ __launch_bounds__(256) void ln_relu(const float* __restrict__ H,
                                               const float* __restrict__ g,
                                               const float* __restrict__ bta,
                                               _Float16* __restrict__ H1,
                                               _Float16* __restrict__ H2) {
  const int row = blockIdx.x;
  const int c = threadIdx.x;
  const int wv = c >> 6, ln = c & 63;
  const float h = H[(size_t)row * DD + c];

  __shared__ float part[4], part2[4];
  float v = h;
#pragma unroll
  for (int off = 32; off > 0; off >>= 1) v += __shfl_xor(v, off);
  if (ln == 0) part[wv] = v;
  __syncthreads();
  const float mu = (part[0] + part[1] + part[2] + part[3]) * (1.0f / 256.0f);

  const float d = h - mu;
  float sq = d * d;
#pragma unroll
  for (int off = 32; off > 0; off >>= 1) sq += __shfl_xor(sq, off);
  if (ln == 0) part2[wv] = sq;
  __syncthreads();
  const float var = (part2[0] + part2[1] + part2[2] + part2[3]) * (1.0f / 256.0f);

  const float y = fmaxf(d * (1.0f / sqrtf(var + 1e-5f)) * g[c] + bta[c], 0.0f);
  _Float16 h1, h2;
  split2(y * 64.0f, h1, h2);
  H1[(size_t)row * DD + c] = h1;
  H2[(size_t)row * DD + c] = h2;
}

// =====================================================================
// Host launch
// =====================================================================
extern "C" void kernel_launch(void* const* d_in, const int* in_sizes, int n_in,
                              void* d_out, int out_size, void* d_ws, size_t ws_size,
                              hipStream_t stream) {
  (void)in_sizes; (void)n_in; (void)out_size; (void)ws_size;
  const float* x   = (const float*)d_in[0];
  const float* wq  = (const float*)d_in[1];
  const float* bq  = (const float*)d_in[2];
  const float* wk  = (const float*)d_in[3];
  const float* bk  = (const float*)d_in[4];
  const float* wv  = (const float*)d_in[5];
  const float* bv  = (const float*)d_in[6];
  const float* adj = (const float*)d_in[7];
  const float* w1  = (const float*)d_in[8];
  const float* b1  = (const float*)d_in[9];
  const float* lng = (const float*)d_in[10];
  const float* lnb = (const float*)d_in[11];
  const float* w2  = (const float*)d_in[12];
  const float* b2  = (const float*)d_in[13];

  const size_t BND = (size_t)MTOT * DD;  // 8,388,608
  float* outp  = (float*)d_out;          // [MTOT][256] (holds V until w2 overwrites)
  float* attnp = outp + BND;             // [MTOT][1024] (S, then attn)
  float* V = outp;

  _Float16* Q1 = (_Float16*)d_ws;  // 68.4 MB total ws use
  _Float16* Q2 = Q1 + BND;
  _Float16* K1 = Q2 + BND;
  _Float16* K2 = K1 + BND;
  _Float16* WT = K2 + BND;  // [5][2][65536]
  _Float16* M1 = Q1;        // reuse after topk (safe: wave reads own Q row first)
  _Float16* M2 = Q2;
  float* H = (float*)K1;    // reuse K region after topk
  _Float16* H1 = Q1;
  _Float16* H2 = Q2;

  const dim3 blk(256);

  prep_w<<<dim3(1280), blk, 0, stream>>>(wq, wk, wv, w1, w2, WT);
  gemm_qkv<<<dim3(1536), blk, 0, stream>>>(x, WT, bq, bk, bv, Q1, Q2, K1, K2, V);
  gemm_split<2><<<dim3(2048), blk, 0, stream>>>(Q1, Q2, K1, K2, adj, nullptr, attnp);
  topk_softmax_msg<<<dim3(MTOT / 4), blk, 0, stream>>>(attnp, V, Q1, Q2, K1, K2, adj, M1, M2);
  gemm_split<0><<<dim3(2, 256), blk, 0, stream>>>(M1, M2, WT + 3 * 131072, WT + 3 * 131072 + 65536,
                                                  b1, nullptr, H);
  ln_relu<<<dim3(MTOT), blk, 0, stream>>>(H, lng, lnb, H1, H2);
  gemm_split<1><<<dim3(2, 256), blk, 0, stream>>>(H1, H2, WT + 4 * 131072, WT + 4 * 131072 + 65536,
                                                  b2, V, outp);
}

// Round 6
// 375.633 us; speedup vs baseline: 1.3006x; 1.3006x over previous
//
#include <hip/hip_runtime.h>
#include <cstdint>

#define NB 32
#define NNODES 1024
#define DD 256
#define KNB 64
#define MTOT (NB * NNODES)  // 32768

// Scaling: activations stored as split(64*a), weights as split(1024*w).
// acc = sum (64a)(1024w) = 65536 * a.w  -> epilogue * 1/65536.
// scores acc = (64q).(64k) = 4096 q.k -> q.k/16 = acc/65536 too.
#define INV65536 1.52587890625e-05f

typedef _Float16 half8 __attribute__((ext_vector_type(8)));
typedef _Float16 half4 __attribute__((ext_vector_type(4)));
typedef float f32x4 __attribute__((ext_vector_type(4)));

typedef __attribute__((address_space(3))) uint32_t lds_u32;
typedef __attribute__((address_space(1))) uint32_t glb_u32;

// 16B async global->LDS. LDS dest wave-uniform; HW adds lane*16.
__device__ __forceinline__ void gll16(const _Float16* g, _Float16* l) {
  __builtin_amdgcn_global_load_lds((const glb_u32*)g, (lds_u32*)l, 16, 0, 0);
}

__device__ __forceinline__ void split2(float v, _Float16& h, _Float16& l) {
  h = (_Float16)v;
  l = (_Float16)(v - (float)h);
}

// =====================================================================
// prep_w: W[k][n] fp32 -> W_T[n][k] fp16x2, scaled by 1024.
// =====================================================================
__global__ __launch_bounds__(256) void prep_w(const float* __restrict__ wq,
                                              const float* __restrict__ wk,
                                              const float* __restrict__ wv,
                                              const float* __restrict__ w1,
                                              const float* __restrict__ w2,
                                              _Float16* __restrict__ WT) {
  const int idx = blockIdx.x * 256 + threadIdx.x;  // < 5*65536
  const int wsel = idx >> 16;
  const int rem = idx & 65535;
  const int k = rem >> 8, n = rem & 255;
  const float* src = (wsel == 0) ? wq : (wsel == 1) ? wk : (wsel == 2) ? wv : (wsel == 3) ? w1 : w2;
  const float v = src[rem] * 1024.0f;
  _Float16 h1, h2;
  split2(v, h1, h2);
  WT[(size_t)wsel * 131072 + n * 256 + k] = h1;
  WT[(size_t)wsel * 131072 + 65536 + n * 256 + k] = h2;
}

// =====================================================================
// prep_x: x fp32 -> X1,X2 = split(64*x) fp16. 8 elems/thread, coalesced.
// =====================================================================
__global__ __launch_bounds__(256) void prep_x(const float* __restrict__ x,
                                              _Float16* __restrict__ X1,
                                              _Float16* __restrict__ X2) {
  const size_t i = ((size_t)blockIdx.x * 256 + threadIdx.x) * 8;
  const float4 a = *(const float4*)(x + i);
  const float4 bb = *(const float4*)(x + i + 4);
  const float vals[8] = {a.x, a.y, a.z, a.w, bb.x, bb.y, bb.z, bb.w};
  half8 h, l;
#pragma unroll
  for (int e = 0; e < 8; ++e) {
    _Float16 hh, ll;
    split2(vals[e] * 64.0f, hh, ll);
    h[e] = hh;
    l[e] = ll;
  }
  *(half8*)(X1 + i) = h;
  *(half8*)(X2 + i) = l;
}

// LDS tile layout: [128 rows][8 chunks of 8 halfs], chunk XOR-swizzled by (row&7)
#define SWZ_OFF(r, cc) ((r) * 64 + (((cc) ^ ((r)&7)) << 3))

// =====================================================================
// gemm_qkv v6: exact gemm_split body (A=X1/X2 pre-split, B=WT, all via
// global_load_lds). Epilogue: Q,K -> split stores; V -> fp32.
// Grid 1D 1536, XCD-swizzled: 6 sibling blocks (same m-rows) per XCD.
// =====================================================================
__global__ __launch_bounds__(256) void gemm_qkv(const _Float16* __restrict__ X1,
                                                const _Float16* __restrict__ X2,
                                                const _Float16* __restrict__ WT,
                                                const float* __restrict__ bq,
                                                const float* __restrict__ bk,
                                                const float* __restrict__ bv,
                                                _Float16* __restrict__ Q1, _Float16* __restrict__ Q2,
                                                _Float16* __restrict__ K1, _Float16* __restrict__ K2,
                                                float* __restrict__ V) {
  __shared__ _Float16 sm[4 * 8192];
  _Float16* sA1 = sm;
  _Float16* sA2 = sm + 8192;
  _Float16* sB1 = sm + 16384;
  _Float16* sB2 = sm + 24576;

  const int tid = threadIdx.x;
  const int lane = tid & 63, w = tid >> 6;
  const int r16 = lane & 15, kg = lane >> 4;
  const int rsub = lane >> 3, csub = lane & 7;
  const int wm = (w >> 1) * 64, wn = (w & 1) * 64;

  // XCD swizzle: id%8 = XCD; 6 siblings (j=0..5) of each m-tile share id%8
  const int id = blockIdx.x;
  const int c8 = id & 7, t = id >> 3;   // t in 0..191
  const int gy = (t / 6) * 8 + c8;      // m-tile 0..255
  const int j6 = t % 6;
  const int wsel = j6 >> 1;
  const int n0 = (j6 & 1) * 128;
  const int m0 = gy * 128;

  const _Float16* pB1 = WT + (size_t)wsel * 131072;
  const _Float16* pB2 = pB1 + 65536;

  f32x4 acc[4][4];
#pragma unroll
  for (int i = 0; i < 4; ++i)
#pragma unroll
    for (int j = 0; j < 4; ++j) acc[i][j] = f32x4{0.f, 0.f, 0.f, 0.f};

  for (int k0 = 0; k0 < DD; k0 += 64) {
    __syncthreads();
#pragma unroll
    for (int it = 0; it < 4; ++it) {
      const int r = (w << 5) + (it << 3) + rsub;
      const int swz = ((csub ^ (r & 7)) << 3);
      const int ldso = (w << 11) + (it << 9);
      gll16(X1 + (size_t)(m0 + r) * DD + k0 + swz, sA1 + ldso);
      gll16(X2 + (size_t)(m0 + r) * DD + k0 + swz, sA2 + ldso);
      gll16(pB1 + (size_t)(n0 + r) * DD + k0 + swz, sB1 + ldso);
      gll16(pB2 + (size_t)(n0 + r) * DD + k0 + swz, sB2 + ldso);
    }
    __syncthreads();

#pragma unroll
    for (int s = 0; s < 2; ++s) {
      half8 aA[4], aB[4], bA[4], bB[4];
#pragma unroll
      for (int mi = 0; mi < 4; ++mi) {
        const int off = SWZ_OFF(wm + mi * 16 + r16, s * 4 + kg);
        aA[mi] = *(const half8*)(sA1 + off);
        aB[mi] = *(const half8*)(sA2 + off);
      }
#pragma unroll
      for (int nj = 0; nj < 4; ++nj) {
        const int off = SWZ_OFF(wn + nj * 16 + r16, s * 4 + kg);
        bA[nj] = *(const half8*)(sB1 + off);
        bB[nj] = *(const half8*)(sB2 + off);
      }
#pragma unroll
      for (int mi = 0; mi < 4; ++mi)
#pragma unroll
        for (int nj = 0; nj < 4; ++nj) {
          acc[mi][nj] = __builtin_amdgcn_mfma_f32_16x16x32_f16(aA[mi], bA[nj], acc[mi][nj], 0, 0, 0);
          acc[mi][nj] = __builtin_amdgcn_mfma_f32_16x16x32_f16(aA[mi], bB[nj], acc[mi][nj], 0, 0, 0);
          acc[mi][nj] = __builtin_amdgcn_mfma_f32_16x16x32_f16(aB[mi], bA[nj], acc[mi][nj], 0, 0, 0);
        }
    }
  }

  const float* bsel = (wsel == 0) ? bq : (wsel == 1) ? bk : bv;
  _Float16* P1 = (wsel == 0) ? Q1 : K1;
  _Float16* P2 = (wsel == 0) ? Q2 : K2;
#pragma unroll
  for (int mi = 0; mi < 4; ++mi)
#pragma unroll
    for (int nj = 0; nj < 4; ++nj) {
      const int col = n0 + wn + nj * 16 + r16;
#pragma unroll
      for (int j = 0; j < 4; ++j) {
        const int rr = m0 + wm + mi * 16 + kg * 4 + j;
        if (wsel == 2) {
          V[(size_t)rr * DD + col] = acc[mi][nj][j] * INV65536 + bsel[col];
        } else {
          // store 64*Q = acc/1024 + 64*bias
          const float qv = acc[mi][nj][j] * (1.0f / 1024.0f) + 64.0f * bsel[col];
          _Float16 h1, h2;
          split2(qv, h1, h2);
          P1[(size_t)rr * DD + col] = h1;
          P2[(size_t)rr * DD + col] = h2;
        }
      }
    }
}

// =====================================================================
// gemm_split<EPI>: A,B pre-split fp16x2, K-major rows (NT).
// EPI 0: C = acc/65536 + bias          (w1 -> H fp32), grid (2,256)
// EPI 1: C = acc/65536 + bias + resid  (w2 -> out fp32), grid (2,256)
// EPI 2: S = acc/65536 + adj           (scores), grid (8,256)
// =====================================================================
template <int EPI>
__global__ __launch_bounds__(256) void gemm_split(const _Float16* __restrict__ A1,
                                                  const _Float16* __restrict__ A2,
                                                  const _Float16* __restrict__ B1g,
                                                  const _Float16* __restrict__ B2g,
                                                  const float* __restrict__ bias,
                                                  const float* __restrict__ resid,
                                                  float* __restrict__ C) {
  __shared__ _Float16 sm[4 * 8192];
  _Float16* sA1 = sm;
  _Float16* sA2 = sm + 8192;
  _Float16* sB1 = sm + 16384;
  _Float16* sB2 = sm + 24576;

  const int tid = threadIdx.x;
  const int lane = tid & 63, w = tid >> 6;
  const int r16 = lane & 15, kg = lane >> 4;
  const int rsub = lane >> 3, csub = lane & 7;
  const int wm = (w >> 1) * 64, wn = (w & 1) * 64;

  const int n0 = blockIdx.x * 128;
  const int m0 = blockIdx.y * 128;

  const _Float16* pB1 = B1g;
  const _Float16* pB2 = B2g;
  if (EPI == 2) {
    const size_t boff = (size_t)(m0 >> 10) * NNODES * DD;
    pB1 += boff;
    pB2 += boff;
  }

  f32x4 acc[4][4];
#pragma unroll
  for (int i = 0; i < 4; ++i)
#pragma unroll
    for (int j = 0; j < 4; ++j) acc[i][j] = f32x4{0.f, 0.f, 0.f, 0.f};

  for (int k0 = 0; k0 < DD; k0 += 64) {
    __syncthreads();
#pragma unroll
    for (int it = 0; it < 4; ++it) {
      const int r = (w << 5) + (it << 3) + rsub;
      const int swz = ((csub ^ (r & 7)) << 3);
      const int ldso = (w << 11) + (it << 9);
      gll16(A1 + (size_t)(m0 + r) * DD + k0 + swz, sA1 + ldso);
      gll16(A2 + (size_t)(m0 + r) * DD + k0 + swz, sA2 + ldso);
      gll16(pB1 + (size_t)(n0 + r) * DD + k0 + swz, sB1 + ldso);
      gll16(pB2 + (size_t)(n0 + r) * DD + k0 + swz, sB2 + ldso);
    }
    __syncthreads();

#pragma unroll
    for (int s = 0; s < 2; ++s) {
      half8 aA[4], aB[4], bA[4], bB[4];
#pragma unroll
      for (int mi = 0; mi < 4; ++mi) {
        const int off = SWZ_OFF(wm + mi * 16 + r16, s * 4 + kg);
        aA[mi] = *(const half8*)(sA1 + off);
        aB[mi] = *(const half8*)(sA2 + off);
      }
#pragma unroll
      for (int nj = 0; nj < 4; ++nj) {
        const int off = SWZ_OFF(wn + nj * 16 + r16, s * 4 + kg);
        bA[nj] = *(const half8*)(sB1 + off);
        bB[nj] = *(const half8*)(sB2 + off);
      }
#pragma unroll
      for (int mi = 0; mi < 4; ++mi)
#pragma unroll
        for (int nj = 0; nj < 4; ++nj) {
          acc[mi][nj] = __builtin_amdgcn_mfma_f32_16x16x32_f16(aA[mi], bA[nj], acc[mi][nj], 0, 0, 0);
          acc[mi][nj] = __builtin_amdgcn_mfma_f32_16x16x32_f16(aA[mi], bB[nj], acc[mi][nj], 0, 0, 0);
          acc[mi][nj] = __builtin_amdgcn_mfma_f32_16x16x32_f16(aB[mi], bA[nj], acc[mi][nj], 0, 0, 0);
        }
    }
  }

#pragma unroll
  for (int mi = 0; mi < 4; ++mi)
#pragma unroll
    for (int nj = 0; nj < 4; ++nj) {
      const int col = n0 + wn + nj * 16 + r16;
#pragma unroll
      for (int j = 0; j < 4; ++j) {
        const int rr = m0 + wm + mi * 16 + kg * 4 + j;
        const float v = acc[mi][nj][j] * INV65536;
        if (EPI == 2) {
          C[(size_t)rr * NNODES + col] = v + bias[(size_t)(rr & (NNODES - 1)) * NNODES + col];
        } else if (EPI == 0) {
          C[(size_t)rr * DD + col] = v + bias[col];
        } else {
          C[(size_t)rr * DD + col] = v + bias[col] + resid[(size_t)rr * DD + col];
        }
      }
    }
}

// =====================================================================
// Top-64 + masked softmax (in-place) + sparse messages. One wave/row.
// 21-bit fixed-point radix keys counted via ballot+popcount; candidates
// near the boundary get exact fp32 recompute (jax tie semantics).
// =====================================================================
__global__ __launch_bounds__(256) void topk_softmax_msg(float* __restrict__ S,
                                                        const float* __restrict__ V,
                                                        const _Float16* __restrict__ Q1,
                                                        const _Float16* __restrict__ Q2,
                                                        const _Float16* __restrict__ K1,
                                                        const _Float16* __restrict__ K2,
                                                        const float* __restrict__ adj,
                                                        _Float16* __restrict__ M1,
                                                        _Float16* __restrict__ M2) {
  const int tid = threadIdx.x;
  const int w = tid >> 6, lane = tid & 63;
  const int row = blockIdx.x * 4 + w;
  const int b = row >> 10;
  const int m = row & (NNODES - 1);
  float* Srow = S + (size_t)row * NNODES;

  __shared__ float2 spair[4][KNB];  // (wgt, idx bits)
  __shared__ int cidxs[4][32];
  __shared__ float cex[4][32];
  __shared__ int csel[4][32];

  if (lane < KNB) spair[w][lane] = make_float2(0.0f, __int_as_float(0));

  float s[16];
#pragma unroll
  for (int c = 0; c < 4; ++c) {
    const float4 sv = *(const float4*)(Srow + c * 256 + lane * 4);
    s[c * 4 + 0] = sv.x;
    s[c * 4 + 1] = sv.y;
    s[c * 4 + 2] = sv.z;
    s[c * 4 + 3] = sv.w;
  }

  unsigned key[16];
#pragma unroll
  for (int t = 0; t < 16; ++t) {
    const float f = fminf(fmaxf((s[t] + 8.0f) * 131072.0f, 0.0f), 2097151.0f);
    key[t] = (unsigned)f;
  }

  unsigned cur = 0u;
#pragma unroll 1
  for (int bit = 20; bit >= 0; --bit) {
    const unsigned cand = cur | (1u << bit);
    int cnt = 0;
#pragma unroll
    for (int t = 0; t < 16; ++t) cnt += (int)__popcll(__ballot(key[t] >= cand));
    if (cnt >= KNB) cur = cand;
  }

  const float s64f = (float)cur * (16.0f / 2097152.0f) - 8.0f;
  const float thrHi = s64f + 6e-5f;
  const float thrLo = s64f - 5e-5f;

  const unsigned long long ltmask = (1ull << lane) - 1ull;
  unsigned hm = 0u, cm = 0u;
  int cpos[16];
  int nhi = 0, ncand = 0;
#pragma unroll
  for (int c = 0; c < 4; ++c) {
    bool hiv[4], cdv[4];
    unsigned long long mh[4], mc[4];
#pragma unroll
    for (int e = 0; e < 4; ++e) {
      const int t = c * 4 + e;
      hiv[e] = (s[t] > thrHi);
      cdv[e] = (!hiv[e]) && (s[t] >= thrLo);
      mh[e] = __ballot(hiv[e]);
      mc[e] = __ballot(cdv[e]);
    }
    const int below = (int)__popcll(mc[0] & ltmask) + (int)__popcll(mc[1] & ltmask) +
                      (int)__popcll(mc[2] & ltmask) + (int)__popcll(mc[3] & ltmask);
    int own = 0;
#pragma unroll
    for (int e = 0; e < 4; ++e) {
      const int t = c * 4 + e;
      cpos[t] = -1;
      if (hiv[e]) hm |= (1u << t);
      if (cdv[e]) {
        cm |= (1u << t);
        const int p = ncand + below + own;
        cpos[t] = p;
        if (p < 32) cidxs[w][p] = c * 256 + lane * 4 + e;
        ++own;
      }
    }
    nhi += (int)__popcll(mh[0]) + (int)__popcll(mh[1]) + (int)__popcll(mh[2]) + (int)__popcll(mh[3]);
    ncand += (int)__popcll(mc[0]) + (int)__popcll(mc[1]) + (int)__popcll(mc[2]) + (int)__popcll(mc[3]);
  }
  const int need = KNB - nhi;

  unsigned selm;
  if (ncand == need) {
    selm = hm | cm;
  } else {
    const int nc = (ncand <= 32) ? ncand : 32;
    const int nd = (need <= nc) ? need : nc;
    const size_t qoff = (size_t)row * DD + lane * 4;
    const half4 q1v = *(const half4*)(Q1 + qoff);
    const half4 q2v = *(const half4*)(Q2 + qoff);
    float qf[4];
#pragma unroll
    for (int e = 0; e < 4; ++e) qf[e] = (float)q1v[e] + (float)q2v[e];
    const float* adjrow = adj + (size_t)m * NNODES;
#pragma unroll 1
    for (int t2 = 0; t2 < nc; ++t2) {
      const int j = cidxs[w][t2];
      const size_t koff = ((size_t)b * NNODES + j) * DD + lane * 4;
      const half4 k1v = *(const half4*)(K1 + koff);
      const half4 k2v = *(const half4*)(K2 + koff);
      float part = 0.0f;
#pragma unroll
      for (int e = 0; e < 4; ++e) part = fmaf(qf[e], (float)k1v[e] + (float)k2v[e], part);
#pragma unroll
      for (int off = 32; off > 0; off >>= 1) part += __shfl_xor(part, off);
      if (lane == 0) cex[w][t2] = part * INV65536 + adjrow[j];
    }
    if (lane < nc) {
      const float et = cex[w][lane];
      int rank = 0;
      for (int u = 0; u < nc; ++u) {
        const float eu = cex[w][u];
        rank += (eu > et || (eu == et && u < lane)) ? 1 : 0;
      }
      csel[w][lane] = (rank < nd) ? 1 : 0;
    }
    selm = hm;
#pragma unroll
    for (int t = 0; t < 16; ++t) {
      if (((cm >> t) & 1u) && cpos[t] >= 0 && cpos[t] < 32 && csel[w][cpos[t]]) selm |= (1u << t);
    }
  }

  float rmax = s[0];
#pragma unroll
  for (int t = 1; t < 16; ++t) rmax = fmaxf(rmax, s[t]);
#pragma unroll
  for (int off = 32; off > 0; off >>= 1) rmax = fmaxf(rmax, __shfl_xor(rmax, off));

  float p[16];
  float sum = 0.0f;
#pragma unroll
  for (int t = 0; t < 16; ++t) {
    p[t] = __expf(s[t] - rmax);
    if ((selm >> t) & 1u) sum += p[t];
  }
#pragma unroll
  for (int off = 32; off > 0; off >>= 1) sum += __shfl_xor(sum, off);
  const float inv = 1.0f / sum;

  int run = 0;
#pragma unroll
  for (int c = 0; c < 4; ++c) {
    bool sel4[4];
    unsigned long long ms[4];
#pragma unroll
    for (int e = 0; e < 4; ++e) {
      sel4[e] = (selm >> (c * 4 + e)) & 1u;
      ms[e] = __ballot(sel4[e]);
    }
    const int below = (int)__popcll(ms[0] & ltmask) + (int)__popcll(ms[1] & ltmask) +
                      (int)__popcll(ms[2] & ltmask) + (int)__popcll(ms[3] & ltmask);
    float4 ow;
    float* owp = (float*)&ow;
    int own = 0;
#pragma unroll
    for (int e = 0; e < 4; ++e) {
      const int t = c * 4 + e;
      const float aw = sel4[e] ? p[t] * inv : 0.0f;
      owp[e] = aw;
      if (sel4[e]) {
        const int pos = run + below + own;
        if (pos < KNB) spair[w][pos] = make_float2(aw, __int_as_float(c * 256 + lane * 4 + e));
        ++own;
      }
    }
    *(float4*)(Srow + c * 256 + lane * 4) = ow;
    run += (int)__popcll(ms[0]) + (int)__popcll(ms[1]) + (int)__popcll(ms[2]) + (int)__popcll(ms[3]);
  }

  const float* Vb = V + (size_t)b * NNODES * DD;
  float4 acc = {0.0f, 0.0f, 0.0f, 0.0f};
#pragma unroll 2
  for (int t = 0; t < KNB; ++t) {
    const float2 pr = spair[w][t];
    const int j = __float_as_int(pr.y);
    const float4 vv = *(const float4*)(Vb + (size_t)j * DD + lane * 4);
    acc.x = fmaf(pr.x, vv.x, acc.x);
    acc.y = fmaf(pr.x, vv.y, acc.y);
    acc.z = fmaf(pr.x, vv.z, acc.z);
    acc.w = fmaf(pr.x, vv.w, acc.w);
  }
  const float av[4] = {acc.x, acc.y, acc.z, acc.w};
  half4 m1, m2;
#pragma unroll
  for (int d = 0; d < 4; ++d) {
    _Float16 a, bb;
    split2(av[d] * 64.0f, a, bb);
    m1[d] = a;
    m2[d] = bb;
  }
  *(half4*)(M1 + (size_t)row * DD + lane * 4) = m1;
  *(half4*)(M2 + (size_t)row * DD + lane * 4) = m2;
}

// =====================================================================
// LayerNorm + ReLU: H fp32 -> split(64*y).
// =====================================================================
__global__ __launch_bounds__(256) void ln_relu(const float* __restrict__ H,
                                               const float* __restrict__ g,
                                               const float* __restrict__ bta,
                                               _Float16* __restrict__ H1,
                                               _Float16* __restrict__ H2) {
  const int row = blockIdx.x;
  const int c = threadIdx.x;
  const int wv = c >> 6, ln = c & 63;
  const float h = H[(size_t)row * DD + c];

  __shared__ float part[4], part2[4];
  float v = h;
#pragma unroll
  for (int off = 32; off > 0; off >>= 1) v += __shfl_xor(v, off);
  if (ln == 0) part[wv] = v;
  __syncthreads();
  const float mu = (part[0] + part[1] + part[2] + part[3]) * (1.0f / 256.0f);

  const float d = h - mu;
  float sq = d * d;
#pragma unroll
  for (int off = 32; off > 0; off >>= 1) sq += __shfl_xor(sq, off);
  if (ln == 0) part2[wv] = sq;
  __syncthreads();
  const float var = (part2[0] + part2[1] + part2[2] + part2[3]) * (1.0f / 256.0f);

  const float y = fmaxf(d * (1.0f / sqrtf(var + 1e-5f)) * g[c] + bta[c], 0.0f);
  _Float16 h1, h2;
  split2(y * 64.0f, h1, h2);
  H1[(size_t)row * DD + c] = h1;
  H2[(size_t)row * DD + c] = h2;
}

// =====================================================================
// Host launch
// =====================================================================
extern "C" void kernel_launch(void* const* d_in, const int* in_sizes, int n_in,
                              void* d_out, int out_size, void* d_ws, size_t ws_size,
                              hipStream_t stream) {
  (void)in_sizes; (void)n_in; (void)out_size; (void)ws_size;
  const float* x   = (const float*)d_in[0];
  const float* wq  = (const float*)d_in[1];
  const float* bq  = (const float*)d_in[2];
  const float* wk  = (const float*)d_in[3];
  const float* bk  = (const float*)d_in[4];
  const float* wv  = (const float*)d_in[5];
  const float* bv  = (const float*)d_in[6];
  const float* adj = (const float*)d_in[7];
  const float* w1  = (const float*)d_in[8];
  const float* b1  = (const float*)d_in[9];
  const float* lng = (const float*)d_in[10];
  const float* lnb = (const float*)d_in[11];
  const float* w2  = (const float*)d_in[12];
  const float* b2  = (const float*)d_in[13];

  const size_t BND = (size_t)MTOT * DD;  // 8,388,608
  float* outp  = (float*)d_out;          // [MTOT][256] (holds V until w2 overwrites)
  float* attnp = outp + BND;             // [MTOT][1024] (X splits, then S, then attn)
  float* V = outp;

  // X1/X2 live in the attn scratch region (dead before scores writes S there)
  _Float16* X1 = (_Float16*)attnp;
  _Float16* X2 = X1 + BND;

  _Float16* Q1 = (_Float16*)d_ws;  // 68.4 MB total ws use
  _Float16* Q2 = Q1 + BND;
  _Float16* K1 = Q2 + BND;
  _Float16* K2 = K1 + BND;
  _Float16* WT = K2 + BND;  // [5][2][65536]
  _Float16* M1 = Q1;        // reuse after topk (safe: wave reads own Q row first)
  _Float16* M2 = Q2;
  float* H = (float*)K1;    // reuse K region after topk
  _Float16* H1 = Q1;
  _Float16* H2 = Q2;

  const dim3 blk(256);

  prep_w<<<dim3(1280), blk, 0, stream>>>(wq, wk, wv, w1, w2, WT);
  prep_x<<<dim3(4096), blk, 0, stream>>>(x, X1, X2);
  gemm_qkv<<<dim3(1536), blk, 0, stream>>>(X1, X2, WT, bq, bk, bv, Q1, Q2, K1, K2, V);
  gemm_split<2><<<dim3(8, 256), blk, 0, stream>>>(Q1, Q2, K1, K2, adj, nullptr, attnp);
  topk_softmax_msg<<<dim3(MTOT / 4), blk, 0, stream>>>(attnp, V, Q1, Q2, K1, K2, adj, M1, M2);
  gemm_split<0><<<dim3(2, 256), blk, 0, stream>>>(M1, M2, WT + 3 * 131072, WT + 3 * 131072 + 65536,
                                                  b1, nullptr, H);
  ln_relu<<<dim3(MTOT), blk, 0, stream>>>(H, lng, lnb, H1, H2);
  gemm_split<1><<<dim3(2, 256), blk, 0, stream>>>(H1, H2, WT + 4 * 131072, WT + 4 * 131072 + 65536,
                                                  b2, V, outp);
}

// Round 7
// 342.118 us; speedup vs baseline: 1.4281x; 1.0980x over previous
//
#include <hip/hip_runtime.h>
#include <cstdint>

#define NB 32
#define NNODES 1024
#define DD 256
#define KNB 64
#define MTOT (NB * NNODES)  // 32768

// Scaling: activations stored as split(64*a), weights as split(1024*w).
// acc = sum (64a)(1024w) = 65536 * a.w  -> epilogue * 1/65536.
// scores acc = (64q).(64k) = 4096 q.k -> q.k/16 = acc/65536 too.
#define INV65536 1.52587890625e-05f
// 16-bit key cell over [-8,8)
#define KCELL 2.44140625e-4f

typedef _Float16 half8 __attribute__((ext_vector_type(8)));
typedef _Float16 half4 __attribute__((ext_vector_type(4)));
typedef float f32x4 __attribute__((ext_vector_type(4)));

typedef __attribute__((address_space(3))) uint32_t lds_u32;
typedef __attribute__((address_space(1))) uint32_t glb_u32;

// 16B async global->LDS. LDS dest wave-uniform; HW adds lane*16.
__device__ __forceinline__ void gll16(const _Float16* g, _Float16* l) {
  __builtin_amdgcn_global_load_lds((const glb_u32*)g, (lds_u32*)l, 16, 0, 0);
}

__device__ __forceinline__ void split2(float v, _Float16& h, _Float16& l) {
  h = (_Float16)v;
  l = (_Float16)(v - (float)h);
}

// =====================================================================
// prep_w: W[k][n] fp32 -> W_T[n][k] fp16x2, scaled by 1024.
// =====================================================================
__global__ __launch_bounds__(256) void prep_w(const float* __restrict__ wq,
                                              const float* __restrict__ wk,
                                              const float* __restrict__ wv,
                                              const float* __restrict__ w1,
                                              const float* __restrict__ w2,
                                              _Float16* __restrict__ WT) {
  const int idx = blockIdx.x * 256 + threadIdx.x;  // < 5*65536
  const int wsel = idx >> 16;
  const int rem = idx & 65535;
  const int k = rem >> 8, n = rem & 255;
  const float* src = (wsel == 0) ? wq : (wsel == 1) ? wk : (wsel == 2) ? wv : (wsel == 3) ? w1 : w2;
  const float v = src[rem] * 1024.0f;
  _Float16 h1, h2;
  split2(v, h1, h2);
  WT[(size_t)wsel * 131072 + n * 256 + k] = h1;
  WT[(size_t)wsel * 131072 + 65536 + n * 256 + k] = h2;
}

// =====================================================================
// prep_x: x fp32 -> X1,X2 = split(64*x) fp16. 8 elems/thread, coalesced.
// =====================================================================
__global__ __launch_bounds__(256) void prep_x(const float* __restrict__ x,
                                              _Float16* __restrict__ X1,
                                              _Float16* __restrict__ X2) {
  const size_t i = ((size_t)blockIdx.x * 256 + threadIdx.x) * 8;
  const float4 a = *(const float4*)(x + i);
  const float4 bb = *(const float4*)(x + i + 4);
  const float vals[8] = {a.x, a.y, a.z, a.w, bb.x, bb.y, bb.z, bb.w};
  half8 h, l;
#pragma unroll
  for (int e = 0; e < 8; ++e) {
    _Float16 hh, ll;
    split2(vals[e] * 64.0f, hh, ll);
    h[e] = hh;
    l[e] = ll;
  }
  *(half8*)(X1 + i) = h;
  *(half8*)(X2 + i) = l;
}

// LDS tile layout: [128 rows][8 chunks of 8 halfs], chunk XOR-swizzled by (row&7)
#define SWZ_OFF(r, cc) ((r) * 64 + (((cc) ^ ((r)&7)) << 3))

// =====================================================================
// gemm_qkv: A=X1/X2 pre-split, B=WT, all via global_load_lds.
// Q,K: 3 products (selection-critical). V: 1 product (A1B1 only; error
// ~3e-3 worst-case << 0.079 output tolerance).
// Grid 1D 1536, XCD-swizzled: 6 sibling blocks (same m-rows) per XCD.
// =====================================================================
__global__ __launch_bounds__(256) void gemm_qkv(const _Float16* __restrict__ X1,
                                                const _Float16* __restrict__ X2,
                                                const _Float16* __restrict__ WT,
                                                const float* __restrict__ bq,
                                                const float* __restrict__ bk,
                                                const float* __restrict__ bv,
                                                _Float16* __restrict__ Q1, _Float16* __restrict__ Q2,
                                                _Float16* __restrict__ K1, _Float16* __restrict__ K2,
                                                float* __restrict__ V) {
  __shared__ _Float16 sm[4 * 8192];
  _Float16* sA1 = sm;
  _Float16* sA2 = sm + 8192;
  _Float16* sB1 = sm + 16384;
  _Float16* sB2 = sm + 24576;

  const int tid = threadIdx.x;
  const int lane = tid & 63, w = tid >> 6;
  const int r16 = lane & 15, kg = lane >> 4;
  const int rsub = lane >> 3, csub = lane & 7;
  const int wm = (w >> 1) * 64, wn = (w & 1) * 64;

  // XCD swizzle: id%8 = XCD; 6 siblings (j=0..5) of each m-tile share id%8
  const int id = blockIdx.x;
  const int c8 = id & 7, t = id >> 3;   // t in 0..191
  const int gy = (t / 6) * 8 + c8;      // m-tile 0..255
  const int j6 = t % 6;
  const int wsel = j6 >> 1;
  const int n0 = (j6 & 1) * 128;
  const int m0 = gy * 128;
  const bool full = (wsel != 2);  // Q,K need 3 products; V needs 1

  const _Float16* pB1 = WT + (size_t)wsel * 131072;
  const _Float16* pB2 = pB1 + 65536;

  f32x4 acc[4][4];
#pragma unroll
  for (int i = 0; i < 4; ++i)
#pragma unroll
    for (int j = 0; j < 4; ++j) acc[i][j] = f32x4{0.f, 0.f, 0.f, 0.f};

  for (int k0 = 0; k0 < DD; k0 += 64) {
    __syncthreads();
#pragma unroll
    for (int it = 0; it < 4; ++it) {
      const int r = (w << 5) + (it << 3) + rsub;
      const int swz = ((csub ^ (r & 7)) << 3);
      const int ldso = (w << 11) + (it << 9);
      gll16(X1 + (size_t)(m0 + r) * DD + k0 + swz, sA1 + ldso);
      gll16(pB1 + (size_t)(n0 + r) * DD + k0 + swz, sB1 + ldso);
      if (full) {
        gll16(X2 + (size_t)(m0 + r) * DD + k0 + swz, sA2 + ldso);
        gll16(pB2 + (size_t)(n0 + r) * DD + k0 + swz, sB2 + ldso);
      }
    }
    __syncthreads();

#pragma unroll
    for (int s = 0; s < 2; ++s) {
      half8 aA[4], aB[4], bA[4], bB[4];
#pragma unroll
      for (int mi = 0; mi < 4; ++mi) {
        const int off = SWZ_OFF(wm + mi * 16 + r16, s * 4 + kg);
        aA[mi] = *(const half8*)(sA1 + off);
      }
#pragma unroll
      for (int nj = 0; nj < 4; ++nj) {
        const int off = SWZ_OFF(wn + nj * 16 + r16, s * 4 + kg);
        bA[nj] = *(const half8*)(sB1 + off);
      }
      if (full) {
#pragma unroll
        for (int mi = 0; mi < 4; ++mi) {
          const int off = SWZ_OFF(wm + mi * 16 + r16, s * 4 + kg);
          aB[mi] = *(const half8*)(sA2 + off);
        }
#pragma unroll
        for (int nj = 0; nj < 4; ++nj) {
          const int off = SWZ_OFF(wn + nj * 16 + r16, s * 4 + kg);
          bB[nj] = *(const half8*)(sB2 + off);
        }
      }
#pragma unroll
      for (int mi = 0; mi < 4; ++mi)
#pragma unroll
        for (int nj = 0; nj < 4; ++nj) {
          acc[mi][nj] = __builtin_amdgcn_mfma_f32_16x16x32_f16(aA[mi], bA[nj], acc[mi][nj], 0, 0, 0);
          if (full) {
            acc[mi][nj] = __builtin_amdgcn_mfma_f32_16x16x32_f16(aA[mi], bB[nj], acc[mi][nj], 0, 0, 0);
            acc[mi][nj] = __builtin_amdgcn_mfma_f32_16x16x32_f16(aB[mi], bA[nj], acc[mi][nj], 0, 0, 0);
          }
        }
    }
  }

  const float* bsel = (wsel == 0) ? bq : (wsel == 1) ? bk : bv;
  _Float16* P1 = (wsel == 0) ? Q1 : K1;
  _Float16* P2 = (wsel == 0) ? Q2 : K2;
#pragma unroll
  for (int mi = 0; mi < 4; ++mi)
#pragma unroll
    for (int nj = 0; nj < 4; ++nj) {
      const int col = n0 + wn + nj * 16 + r16;
#pragma unroll
      for (int j = 0; j < 4; ++j) {
        const int rr = m0 + wm + mi * 16 + kg * 4 + j;
        if (wsel == 2) {
          V[(size_t)rr * DD + col] = acc[mi][nj][j] * INV65536 + bsel[col];
        } else {
          // store 64*Q = acc/1024 + 64*bias
          const float qv = acc[mi][nj][j] * (1.0f / 1024.0f) + 64.0f * bsel[col];
          _Float16 h1, h2;
          split2(qv, h1, h2);
          P1[(size_t)rr * DD + col] = h1;
          P2[(size_t)rr * DD + col] = h2;
        }
      }
    }
}

// =====================================================================
// gemm_split<EPI>: A,B pre-split fp16x2, K-major rows (NT).
// EPI 0: C = acc/65536 + bias          (w1 -> H fp32), 2 products (A1 only)
// EPI 1: C = acc/65536 + bias + resid  (w2 -> out),    2 products (A1 only)
// EPI 2: scores -> u16 keys written INSIDE each attn row's footprint
//        (bytes 2048..4095 of row's 4KB), 3 products.
// =====================================================================
template <int EPI>
__global__ __launch_bounds__(256) void gemm_split(const _Float16* __restrict__ A1,
                                                  const _Float16* __restrict__ A2,
                                                  const _Float16* __restrict__ B1g,
                                                  const _Float16* __restrict__ B2g,
                                                  const float* __restrict__ bias,
                                                  const float* __restrict__ resid,
                                                  float* __restrict__ C) {
  __shared__ _Float16 sm[4 * 8192];
  _Float16* sA1 = sm;
  _Float16* sA2 = sm + 8192;
  _Float16* sB1 = sm + 16384;
  _Float16* sB2 = sm + 24576;

  const int tid = threadIdx.x;
  const int lane = tid & 63, w = tid >> 6;
  const int r16 = lane & 15, kg = lane >> 4;
  const int rsub = lane >> 3, csub = lane & 7;
  const int wm = (w >> 1) * 64, wn = (w & 1) * 64;

  const int n0 = blockIdx.x * 128;
  const int m0 = blockIdx.y * 128;

  const _Float16* pB1 = B1g;
  const _Float16* pB2 = B2g;
  if (EPI == 2) {
    const size_t boff = (size_t)(m0 >> 10) * NNODES * DD;
    pB1 += boff;
    pB2 += boff;
  }

  f32x4 acc[4][4];
#pragma unroll
  for (int i = 0; i < 4; ++i)
#pragma unroll
    for (int j = 0; j < 4; ++j) acc[i][j] = f32x4{0.f, 0.f, 0.f, 0.f};

  for (int k0 = 0; k0 < DD; k0 += 64) {
    __syncthreads();
#pragma unroll
    for (int it = 0; it < 4; ++it) {
      const int r = (w << 5) + (it << 3) + rsub;
      const int swz = ((csub ^ (r & 7)) << 3);
      const int ldso = (w << 11) + (it << 9);
      gll16(A1 + (size_t)(m0 + r) * DD + k0 + swz, sA1 + ldso);
      if (EPI == 2) gll16(A2 + (size_t)(m0 + r) * DD + k0 + swz, sA2 + ldso);
      gll16(pB1 + (size_t)(n0 + r) * DD + k0 + swz, sB1 + ldso);
      gll16(pB2 + (size_t)(n0 + r) * DD + k0 + swz, sB2 + ldso);
    }
    __syncthreads();

#pragma unroll
    for (int s = 0; s < 2; ++s) {
      half8 aA[4], aB[4], bA[4], bB[4];
#pragma unroll
      for (int mi = 0; mi < 4; ++mi) {
        const int off = SWZ_OFF(wm + mi * 16 + r16, s * 4 + kg);
        aA[mi] = *(const half8*)(sA1 + off);
        if (EPI == 2) aB[mi] = *(const half8*)(sA2 + off);
      }
#pragma unroll
      for (int nj = 0; nj < 4; ++nj) {
        const int off = SWZ_OFF(wn + nj * 16 + r16, s * 4 + kg);
        bA[nj] = *(const half8*)(sB1 + off);
        bB[nj] = *(const half8*)(sB2 + off);
      }
#pragma unroll
      for (int mi = 0; mi < 4; ++mi)
#pragma unroll
        for (int nj = 0; nj < 4; ++nj) {
          acc[mi][nj] = __builtin_amdgcn_mfma_f32_16x16x32_f16(aA[mi], bA[nj], acc[mi][nj], 0, 0, 0);
          acc[mi][nj] = __builtin_amdgcn_mfma_f32_16x16x32_f16(aA[mi], bB[nj], acc[mi][nj], 0, 0, 0);
          if (EPI == 2)
            acc[mi][nj] = __builtin_amdgcn_mfma_f32_16x16x32_f16(aB[mi], bA[nj], acc[mi][nj], 0, 0, 0);
        }
    }
  }

#pragma unroll
  for (int mi = 0; mi < 4; ++mi)
#pragma unroll
    for (int nj = 0; nj < 4; ++nj) {
      const int col = n0 + wn + nj * 16 + r16;
#pragma unroll
      for (int j = 0; j < 4; ++j) {
        const int rr = m0 + wm + mi * 16 + kg * 4 + j;
        const float v = acc[mi][nj][j] * INV65536;
        if (EPI == 2) {
          // key = floor((s+8)/KCELL), clamped to u16
          const float sv = v + bias[(size_t)(rr & (NNODES - 1)) * NNODES + col];
          const float f = fminf(fmaxf((sv + 8.0f) * 4096.0f, 0.0f), 65535.0f);
          uint16_t* kbase = (uint16_t*)((char*)C + (size_t)rr * 4096 + 2048);
          kbase[col] = (uint16_t)(unsigned)f;
        } else if (EPI == 0) {
          C[(size_t)rr * DD + col] = v + bias[col];
        } else {
          C[(size_t)rr * DD + col] = v + bias[col] + resid[(size_t)rr * DD + col];
        }
      }
    }
}

// =====================================================================
// Top-64 from u16 keys + masked softmax + sparse messages. One wave/row.
// Keys at row*4096+2048 (inside this row's attn footprint; wave reads its
// own keys then overwrites the full row -> no cross-block aliasing).
// k64 via 16-iter radix (ballot+popcount). hi: key>=k64+2 (provably in);
// out: key<=k64-2 (provably out); candidates {k64-1,k64,k64+1}: exact
// fp32 recompute from split Q,K; rank (score desc, index asc) = jax.
// Element order: col = g*512 + lane*8 + e; compaction ascending-col.
// =====================================================================
__global__ __launch_bounds__(256) void topk_softmax_msg(float* __restrict__ S,
                                                        const float* __restrict__ V,
                                                        const _Float16* __restrict__ Q1,
                                                        const _Float16* __restrict__ Q2,
                                                        const _Float16* __restrict__ K1,
                                                        const _Float16* __restrict__ K2,
                                                        const float* __restrict__ adj,
                                                        _Float16* __restrict__ M1) {
  const int tid = threadIdx.x;
  const int w = tid >> 6, lane = tid & 63;
  const int row = blockIdx.x * 4 + w;
  const int b = row >> 10;
  const int m = row & (NNODES - 1);
  float* Srow = S + (size_t)row * NNODES;
  const uint16_t* krow = (const uint16_t*)((const char*)S + (size_t)row * 4096 + 2048);

  __shared__ float2 spair[4][KNB];  // (wgt, idx bits)
  __shared__ int cidxs[4][32];
  __shared__ float cex[4][32];
  __shared__ int csel[4][32];

  if (lane < KNB) spair[w][lane] = make_float2(0.0f, __int_as_float(0));

  // load 16 keys: cols g*512 + lane*8 + e
  const uint4 u0 = *(const uint4*)(krow + lane * 8);
  const uint4 u1 = *(const uint4*)(krow + 512 + lane * 8);
  int k[16];
  {
    const unsigned uu[8] = {u0.x, u0.y, u0.z, u0.w, u1.x, u1.y, u1.z, u1.w};
#pragma unroll
    for (int q = 0; q < 8; ++q) {
      k[q * 2] = (int)(uu[q] & 0xffffu);
      k[q * 2 + 1] = (int)(uu[q] >> 16);
    }
  }
  // NOTE: uu order gives k[t]: t = g*8+e with pairs (e even/odd) consecutive:
  // uu[0]=cols lane*8+0,1 ; uu[3]=cols lane*8+6,7 ; uu[4]=cols 512+lane*8+0,1
  // so k[t] maps to col(t) = (t>>3)*512 + lane*8 + (t&7).  (t ascending = col ascending per lane)

  float st[16];
#pragma unroll
  for (int t = 0; t < 16; ++t) st[t] = fmaf((float)k[t] + 0.5f, KCELL, -8.0f);

  // radix-select 64th-largest key (16 bits)
  int cur = 0;
#pragma unroll 1
  for (int bit = 15; bit >= 0; --bit) {
    const int cand = cur | (1 << bit);
    int cnt = 0;
#pragma unroll
    for (int t = 0; t < 16; ++t) cnt += (int)__popcll(__ballot(k[t] >= cand));
    if (cnt >= KNB) cur = cand;
  }

  const int kHi = cur + 2;   // key >= kHi  -> provably in top-64
  const int kLo = cur - 1;   // key <  kLo  -> provably out

  const unsigned long long ltmask = (1ull << lane) - 1ull;
  unsigned hm = 0u, cm = 0u;
  int cpos[16];
  int nhi = 0, ncand = 0;
#pragma unroll
  for (int g = 0; g < 2; ++g) {
    bool hiv[8], cdv[8];
    unsigned long long mh[8], mc[8];
#pragma unroll
    for (int e = 0; e < 8; ++e) {
      const int t = g * 8 + e;
      hiv[e] = (k[t] >= kHi);
      cdv[e] = (!hiv[e]) && (k[t] >= kLo);
      mh[e] = __ballot(hiv[e]);
      mc[e] = __ballot(cdv[e]);
    }
    int below = 0, tot_h = 0, tot_c = 0;
#pragma unroll
    for (int e = 0; e < 8; ++e) {
      below += (int)__popcll(mc[e] & ltmask);
      tot_h += (int)__popcll(mh[e]);
      tot_c += (int)__popcll(mc[e]);
    }
    int own = 0;
#pragma unroll
    for (int e = 0; e < 8; ++e) {
      const int t = g * 8 + e;
      cpos[t] = -1;
      if (hiv[e]) hm |= (1u << t);
      if (cdv[e]) {
        cm |= (1u << t);
        const int p = ncand + below + own;
        cpos[t] = p;
        if (p < 32) cidxs[w][p] = g * 512 + lane * 8 + e;
        ++own;
      }
    }
    nhi += tot_h;
    ncand += tot_c;
  }
  const int need = KNB - nhi;  // >= 1; nhi+ncand >= 64

  unsigned selm;
  if (ncand == need) {
    selm = hm | cm;  // fast path
  } else {
    const int nc = (ncand <= 32) ? ncand : 32;
    const int nd = (need <= nc) ? need : nc;
    const size_t qoff = (size_t)row * DD + lane * 4;
    const half4 q1v = *(const half4*)(Q1 + qoff);
    const half4 q2v = *(const half4*)(Q2 + qoff);
    float qf[4];
#pragma unroll
    for (int e = 0; e < 4; ++e) qf[e] = (float)q1v[e] + (float)q2v[e];
    const float* adjrow = adj + (size_t)m * NNODES;
#pragma unroll 1
    for (int t2 = 0; t2 < nc; ++t2) {
      const int j = cidxs[w][t2];
      const size_t koff = ((size_t)b * NNODES + j) * DD + lane * 4;
      const half4 k1v = *(const half4*)(K1 + koff);
      const half4 k2v = *(const half4*)(K2 + koff);
      float part = 0.0f;
#pragma unroll
      for (int e = 0; e < 4; ++e) part = fmaf(qf[e], (float)k1v[e] + (float)k2v[e], part);
#pragma unroll
      for (int off = 32; off > 0; off >>= 1) part += __shfl_xor(part, off);
      if (lane == 0) cex[w][t2] = part * INV65536 + adjrow[j];
    }
    if (lane < nc) {
      const float et = cex[w][lane];
      int rank = 0;
      for (int u = 0; u < nc; ++u) {
        const float eu = cex[w][u];
        rank += (eu > et || (eu == et && u < lane)) ? 1 : 0;
      }
      csel[w][lane] = (rank < nd) ? 1 : 0;
    }
    selm = hm;
#pragma unroll
    for (int t = 0; t < 16; ++t) {
      if (((cm >> t) & 1u) && cpos[t] >= 0 && cpos[t] < 32 && csel[w][cpos[t]]) selm |= (1u << t);
    }
  }

  // softmax over selected (rmax over all; the max element is hi|cand)
  float rmax = st[0];
#pragma unroll
  for (int t = 1; t < 16; ++t) rmax = fmaxf(rmax, st[t]);
#pragma unroll
  for (int off = 32; off > 0; off >>= 1) rmax = fmaxf(rmax, __shfl_xor(rmax, off));

  float p[16];
  float sum = 0.0f;
#pragma unroll
  for (int t = 0; t < 16; ++t) {
    p[t] = __expf(st[t] - rmax);
    if ((selm >> t) & 1u) sum += p[t];
  }
#pragma unroll
  for (int off = 32; off > 0; off >>= 1) sum += __shfl_xor(sum, off);
  const float inv = 1.0f / sum;

  // attn write (overwrites full 4KB row incl. key half) + ordered compaction
  int run = 0;
#pragma unroll
  for (int g = 0; g < 2; ++g) {
    bool sel8[8];
    unsigned long long ms[8];
#pragma unroll
    for (int e = 0; e < 8; ++e) {
      sel8[e] = (selm >> (g * 8 + e)) & 1u;
      ms[e] = __ballot(sel8[e]);
    }
    int below = 0, tot = 0;
#pragma unroll
    for (int e = 0; e < 8; ++e) {
      below += (int)__popcll(ms[e] & ltmask);
      tot += (int)__popcll(ms[e]);
    }
    float ow[8];
    int own = 0;
#pragma unroll
    for (int e = 0; e < 8; ++e) {
      const int t = g * 8 + e;
      const float aw = sel8[e] ? p[t] * inv : 0.0f;
      ow[e] = aw;
      if (sel8[e]) {
        const int pos = run + below + own;
        if (pos < KNB) spair[w][pos] = make_float2(aw, __int_as_float(g * 512 + lane * 8 + e));
        ++own;
      }
    }
    float* dst = Srow + g * 512 + lane * 8;
    *(float4*)(dst) = make_float4(ow[0], ow[1], ow[2], ow[3]);
    *(float4*)(dst + 4) = make_float4(ow[4], ow[5], ow[6], ow[7]);
    run += tot;
  }

  // messages: lane owns output dims [lane*4, lane*4+4)
  const float* Vb = V + (size_t)b * NNODES * DD;
  float4 acc = {0.0f, 0.0f, 0.0f, 0.0f};
#pragma unroll 2
  for (int t = 0; t < KNB; ++t) {
    const float2 pr = spair[w][t];
    const int j = __float_as_int(pr.y);
    const float4 vv = *(const float4*)(Vb + (size_t)j * DD + lane * 4);
    acc.x = fmaf(pr.x, vv.x, acc.x);
    acc.y = fmaf(pr.x, vv.y, acc.y);
    acc.z = fmaf(pr.x, vv.z, acc.z);
    acc.w = fmaf(pr.x, vv.w, acc.w);
  }
  // M stored as single fp16(64*m) -- downstream w1 runs 2-product (A1 only)
  half4 m1;
  m1[0] = (_Float16)(acc.x * 64.0f);
  m1[1] = (_Float16)(acc.y * 64.0f);
  m1[2] = (_Float16)(acc.z * 64.0f);
  m1[3] = (_Float16)(acc.w * 64.0f);
  *(half4*)(M1 + (size_t)row * DD + lane * 4) = m1;
}

// =====================================================================
// LayerNorm + ReLU: H fp32 -> single fp16(64*y).
// =====================================================================
__global__ __launch_bounds__(256) void ln_relu(const float* __restrict__ H,
                                               const float* __restrict__ g,
                                               const float* __restrict__ bta,
                                               _Float16* __restrict__ H1) {
  const int row = blockIdx.x;
  const int c = threadIdx.x;
  const int wv = c >> 6, ln = c & 63;
  const float h = H[(size_t)row * DD + c];

  __shared__ float part[4], part2[4];
  float v = h;
#pragma unroll
  for (int off = 32; off > 0; off >>= 1) v += __shfl_xor(v, off);
  if (ln == 0) part[wv] = v;
  __syncthreads();
  const float mu = (part[0] + part[1] + part[2] + part[3]) * (1.0f / 256.0f);

  const float d = h - mu;
  float sq = d * d;
#pragma unroll
  for (int off = 32; off > 0; off >>= 1) sq += __shfl_xor(sq, off);
  if (ln == 0) part2[wv] = sq;
  __syncthreads();
  const float var = (part2[0] + part2[1] + part2[2] + part2[3]) * (1.0f / 256.0f);

  const float y = fmaxf(d * (1.0f / sqrtf(var + 1e-5f)) * g[c] + bta[c], 0.0f);
  H1[(size_t)row * DD + c] = (_Float16)(y * 64.0f);
}

// =====================================================================
// Host launch
// =====================================================================
extern "C" void kernel_launch(void* const* d_in, const int* in_sizes, int n_in,
                              void* d_out, int out_size, void* d_ws, size_t ws_size,
                              hipStream_t stream) {
  (void)in_sizes; (void)n_in; (void)out_size; (void)ws_size;
  const float* x   = (const float*)d_in[0];
  const float* wq  = (const float*)d_in[1];
  const float* bq  = (const float*)d_in[2];
  const float* wk  = (const float*)d_in[3];
  const float* bk  = (const float*)d_in[4];
  const float* wv  = (const float*)d_in[5];
  const float* bv  = (const float*)d_in[6];
  const float* adj = (const float*)d_in[7];
  const float* w1  = (const float*)d_in[8];
  const float* b1  = (const float*)d_in[9];
  const float* lng = (const float*)d_in[10];
  const float* lnb = (const float*)d_in[11];
  const float* w2  = (const float*)d_in[12];
  const float* b2  = (const float*)d_in[13];

  const size_t BND = (size_t)MTOT * DD;  // 8,388,608
  float* outp  = (float*)d_out;          // [MTOT][256] (holds V until w2 overwrites)
  float* attnp = outp + BND;             // [MTOT][1024] (X splits -> keys+attn)
  float* V = outp;

  // X1/X2 live in the attn scratch region (dead before scores writes keys)
  _Float16* X1 = (_Float16*)attnp;
  _Float16* X2 = X1 + BND;

  _Float16* Q1 = (_Float16*)d_ws;  // 68.4 MB total ws use
  _Float16* Q2 = Q1 + BND;
  _Float16* K1 = Q2 + BND;
  _Float16* K2 = K1 + BND;
  _Float16* WT = K2 + BND;  // [5][2][65536]
  _Float16* M1 = Q1;        // reuse after topk (wave reads own Q row first)
  float* H = (float*)K1;    // reuse K region after topk
  _Float16* H1 = Q1;        // reuse after w1 consumed M1

  const dim3 blk(256);

  prep_w<<<dim3(1280), blk, 0, stream>>>(wq, wk, wv, w1, w2, WT);
  prep_x<<<dim3(4096), blk, 0, stream>>>(x, X1, X2);
  gemm_qkv<<<dim3(1536), blk, 0, stream>>>(X1, X2, WT, bq, bk, bv, Q1, Q2, K1, K2, V);
  gemm_split<2><<<dim3(8, 256), blk, 0, stream>>>(Q1, Q2, K1, K2, adj, nullptr, attnp);
  topk_softmax_msg<<<dim3(MTOT / 4), blk, 0, stream>>>(attnp, V, Q1, Q2, K1, K2, adj, M1);
  gemm_split<0><<<dim3(2, 256), blk, 0, stream>>>(M1, nullptr, WT + 3 * 131072,
                                                  WT + 3 * 131072 + 65536, b1, nullptr, H);
  ln_relu<<<dim3(MTOT), blk, 0, stream>>>(H, lng, lnb, H1);
  gemm_split<1><<<dim3(2, 256), blk, 0, stream>>>(H1, nullptr, WT + 4 * 131072,
                                                  WT + 4 * 131072 + 65536, b2, V, outp);
}

// Round 8
// 338.618 us; speedup vs baseline: 1.4428x; 1.0103x over previous
//
#include <hip/hip_runtime.h>
#include <cstdint>

#define NB 32
#define NNODES 1024
#define DD 256
#define KNB 64
#define MTOT (NB * NNODES)  // 32768

// Scaling: activations stored as split(64*a), weights as split(1024*w).
// acc = sum (64a)(1024w) = 65536 * a.w  -> epilogue * 1/65536.
// scores acc = (64q).(64k) = 4096 q.k -> q.k/16 = acc/65536 too.
#define INV65536 1.52587890625e-05f
// 16-bit key cell over [-8,8)
#define KCELL 2.44140625e-4f

typedef _Float16 half8 __attribute__((ext_vector_type(8)));
typedef _Float16 half4 __attribute__((ext_vector_type(4)));
typedef float f32x4 __attribute__((ext_vector_type(4)));

typedef __attribute__((address_space(3))) uint32_t lds_u32;
typedef __attribute__((address_space(1))) uint32_t glb_u32;

// 16B async global->LDS. LDS dest wave-uniform; HW adds lane*16.
__device__ __forceinline__ void gll16(const _Float16* g, _Float16* l) {
  __builtin_amdgcn_global_load_lds((const glb_u32*)g, (lds_u32*)l, 16, 0, 0);
}

__device__ __forceinline__ void split2(float v, _Float16& h, _Float16& l) {
  h = (_Float16)v;
  l = (_Float16)(v - (float)h);
}

// =====================================================================
// prep_w: W[k][n] fp32 -> W_T[n][k] fp16x2, scaled by 1024.
// =====================================================================
__global__ __launch_bounds__(256) void prep_w(const float* __restrict__ wq,
                                              const float* __restrict__ wk,
                                              const float* __restrict__ wv,
                                              const float* __restrict__ w1,
                                              const float* __restrict__ w2,
                                              _Float16* __restrict__ WT) {
  const int idx = blockIdx.x * 256 + threadIdx.x;  // < 5*65536
  const int wsel = idx >> 16;
  const int rem = idx & 65535;
  const int k = rem >> 8, n = rem & 255;
  const float* src = (wsel == 0) ? wq : (wsel == 1) ? wk : (wsel == 2) ? wv : (wsel == 3) ? w1 : w2;
  const float v = src[rem] * 1024.0f;
  _Float16 h1, h2;
  split2(v, h1, h2);
  WT[(size_t)wsel * 131072 + n * 256 + k] = h1;
  WT[(size_t)wsel * 131072 + 65536 + n * 256 + k] = h2;
}

// =====================================================================
// prep_x: x fp32 -> X1,X2 = split(64*x) fp16. 8 elems/thread, coalesced.
// =====================================================================
__global__ __launch_bounds__(256) void prep_x(const float* __restrict__ x,
                                              _Float16* __restrict__ X1,
                                              _Float16* __restrict__ X2) {
  const size_t i = ((size_t)blockIdx.x * 256 + threadIdx.x) * 8;
  const float4 a = *(const float4*)(x + i);
  const float4 bb = *(const float4*)(x + i + 4);
  const float vals[8] = {a.x, a.y, a.z, a.w, bb.x, bb.y, bb.z, bb.w};
  half8 h, l;
#pragma unroll
  for (int e = 0; e < 8; ++e) {
    _Float16 hh, ll;
    split2(vals[e] * 64.0f, hh, ll);
    h[e] = hh;
    l[e] = ll;
  }
  *(half8*)(X1 + i) = h;
  *(half8*)(X2 + i) = l;
}

// LDS tile layout: [128 rows][8 chunks of 8 halfs], chunk XOR-swizzled by (row&7)
#define SWZ_OFF(r, cc) ((r) * 64 + (((cc) ^ ((r)&7)) << 3))

// =====================================================================
// gemm_qkv: A=X1/X2 pre-split, B=WT, all via global_load_lds.
// Q,K: 3 products (selection-critical). V: 1 product + optional fp16
// shadow copy V16 for the topk gather (halves L2 gather traffic).
// Grid 1D 1536, XCD-swizzled: 6 sibling blocks (same m-rows) per XCD.
// =====================================================================
__global__ __launch_bounds__(256) void gemm_qkv(const _Float16* __restrict__ X1,
                                                const _Float16* __restrict__ X2,
                                                const _Float16* __restrict__ WT,
                                                const float* __restrict__ bq,
                                                const float* __restrict__ bk,
                                                const float* __restrict__ bv,
                                                _Float16* __restrict__ Q1, _Float16* __restrict__ Q2,
                                                _Float16* __restrict__ K1, _Float16* __restrict__ K2,
                                                float* __restrict__ V,
                                                _Float16* __restrict__ V16) {
  __shared__ _Float16 sm[4 * 8192];
  _Float16* sA1 = sm;
  _Float16* sA2 = sm + 8192;
  _Float16* sB1 = sm + 16384;
  _Float16* sB2 = sm + 24576;

  const int tid = threadIdx.x;
  const int lane = tid & 63, w = tid >> 6;
  const int r16 = lane & 15, kg = lane >> 4;
  const int rsub = lane >> 3, csub = lane & 7;
  const int wm = (w >> 1) * 64, wn = (w & 1) * 64;

  // XCD swizzle: id%8 = XCD; 6 siblings (j=0..5) of each m-tile share id%8
  const int id = blockIdx.x;
  const int c8 = id & 7, t = id >> 3;   // t in 0..191
  const int gy = (t / 6) * 8 + c8;      // m-tile 0..255
  const int j6 = t % 6;
  const int wsel = j6 >> 1;
  const int n0 = (j6 & 1) * 128;
  const int m0 = gy * 128;
  const bool full = (wsel != 2);  // Q,K need 3 products; V needs 1

  const _Float16* pB1 = WT + (size_t)wsel * 131072;
  const _Float16* pB2 = pB1 + 65536;

  f32x4 acc[4][4];
#pragma unroll
  for (int i = 0; i < 4; ++i)
#pragma unroll
    for (int j = 0; j < 4; ++j) acc[i][j] = f32x4{0.f, 0.f, 0.f, 0.f};

  for (int k0 = 0; k0 < DD; k0 += 64) {
    __syncthreads();
#pragma unroll
    for (int it = 0; it < 4; ++it) {
      const int r = (w << 5) + (it << 3) + rsub;
      const int swz = ((csub ^ (r & 7)) << 3);
      const int ldso = (w << 11) + (it << 9);
      gll16(X1 + (size_t)(m0 + r) * DD + k0 + swz, sA1 + ldso);
      gll16(pB1 + (size_t)(n0 + r) * DD + k0 + swz, sB1 + ldso);
      if (full) {
        gll16(X2 + (size_t)(m0 + r) * DD + k0 + swz, sA2 + ldso);
        gll16(pB2 + (size_t)(n0 + r) * DD + k0 + swz, sB2 + ldso);
      }
    }
    __syncthreads();

#pragma unroll
    for (int s = 0; s < 2; ++s) {
      half8 aA[4], aB[4], bA[4], bB[4];
#pragma unroll
      for (int mi = 0; mi < 4; ++mi) {
        const int off = SWZ_OFF(wm + mi * 16 + r16, s * 4 + kg);
        aA[mi] = *(const half8*)(sA1 + off);
      }
#pragma unroll
      for (int nj = 0; nj < 4; ++nj) {
        const int off = SWZ_OFF(wn + nj * 16 + r16, s * 4 + kg);
        bA[nj] = *(const half8*)(sB1 + off);
      }
      if (full) {
#pragma unroll
        for (int mi = 0; mi < 4; ++mi) {
          const int off = SWZ_OFF(wm + mi * 16 + r16, s * 4 + kg);
          aB[mi] = *(const half8*)(sA2 + off);
        }
#pragma unroll
        for (int nj = 0; nj < 4; ++nj) {
          const int off = SWZ_OFF(wn + nj * 16 + r16, s * 4 + kg);
          bB[nj] = *(const half8*)(sB2 + off);
        }
      }
#pragma unroll
      for (int mi = 0; mi < 4; ++mi)
#pragma unroll
        for (int nj = 0; nj < 4; ++nj) {
          acc[mi][nj] = __builtin_amdgcn_mfma_f32_16x16x32_f16(aA[mi], bA[nj], acc[mi][nj], 0, 0, 0);
          if (full) {
            acc[mi][nj] = __builtin_amdgcn_mfma_f32_16x16x32_f16(aA[mi], bB[nj], acc[mi][nj], 0, 0, 0);
            acc[mi][nj] = __builtin_amdgcn_mfma_f32_16x16x32_f16(aB[mi], bA[nj], acc[mi][nj], 0, 0, 0);
          }
        }
    }
  }

  const float* bsel = (wsel == 0) ? bq : (wsel == 1) ? bk : bv;
  _Float16* P1 = (wsel == 0) ? Q1 : K1;
  _Float16* P2 = (wsel == 0) ? Q2 : K2;
#pragma unroll
  for (int mi = 0; mi < 4; ++mi)
#pragma unroll
    for (int nj = 0; nj < 4; ++nj) {
      const int col = n0 + wn + nj * 16 + r16;
#pragma unroll
      for (int j = 0; j < 4; ++j) {
        const int rr = m0 + wm + mi * 16 + kg * 4 + j;
        if (wsel == 2) {
          const float val = acc[mi][nj][j] * INV65536 + bsel[col];
          V[(size_t)rr * DD + col] = val;
          if (V16) V16[(size_t)rr * DD + col] = (_Float16)val;
        } else {
          // store 64*Q = acc/1024 + 64*bias
          const float qv = acc[mi][nj][j] * (1.0f / 1024.0f) + 64.0f * bsel[col];
          _Float16 h1, h2;
          split2(qv, h1, h2);
          P1[(size_t)rr * DD + col] = h1;
          P2[(size_t)rr * DD + col] = h2;
        }
      }
    }
}

// =====================================================================
// gemm_split<EPI>: A,B pre-split fp16x2, K-major rows (NT).
// EPI 0: C = acc/65536 + bias          (w1 -> H fp32), 2 products (A1 only)
// EPI 1: C = acc/65536 + bias + resid  (w2 -> out),    2 products (A1 only)
// EPI 2: scores -> u16 keys written INSIDE each attn row's footprint
//        (bytes 2048..4095 of row's 4KB), 3 products.
// =====================================================================
template <int EPI>
__global__ __launch_bounds__(256) void gemm_split(const _Float16* __restrict__ A1,
                                                  const _Float16* __restrict__ A2,
                                                  const _Float16* __restrict__ B1g,
                                                  const _Float16* __restrict__ B2g,
                                                  const float* __restrict__ bias,
                                                  const float* __restrict__ resid,
                                                  float* __restrict__ C) {
  __shared__ _Float16 sm[4 * 8192];
  _Float16* sA1 = sm;
  _Float16* sA2 = sm + 8192;
  _Float16* sB1 = sm + 16384;
  _Float16* sB2 = sm + 24576;

  const int tid = threadIdx.x;
  const int lane = tid & 63, w = tid >> 6;
  const int r16 = lane & 15, kg = lane >> 4;
  const int rsub = lane >> 3, csub = lane & 7;
  const int wm = (w >> 1) * 64, wn = (w & 1) * 64;

  const int n0 = blockIdx.x * 128;
  const int m0 = blockIdx.y * 128;

  const _Float16* pB1 = B1g;
  const _Float16* pB2 = B2g;
  if (EPI == 2) {
    const size_t boff = (size_t)(m0 >> 10) * NNODES * DD;
    pB1 += boff;
    pB2 += boff;
  }

  f32x4 acc[4][4];
#pragma unroll
  for (int i = 0; i < 4; ++i)
#pragma unroll
    for (int j = 0; j < 4; ++j) acc[i][j] = f32x4{0.f, 0.f, 0.f, 0.f};

  for (int k0 = 0; k0 < DD; k0 += 64) {
    __syncthreads();
#pragma unroll
    for (int it = 0; it < 4; ++it) {
      const int r = (w << 5) + (it << 3) + rsub;
      const int swz = ((csub ^ (r & 7)) << 3);
      const int ldso = (w << 11) + (it << 9);
      gll16(A1 + (size_t)(m0 + r) * DD + k0 + swz, sA1 + ldso);
      if (EPI == 2) gll16(A2 + (size_t)(m0 + r) * DD + k0 + swz, sA2 + ldso);
      gll16(pB1 + (size_t)(n0 + r) * DD + k0 + swz, sB1 + ldso);
      gll16(pB2 + (size_t)(n0 + r) * DD + k0 + swz, sB2 + ldso);
    }
    __syncthreads();

#pragma unroll
    for (int s = 0; s < 2; ++s) {
      half8 aA[4], aB[4], bA[4], bB[4];
#pragma unroll
      for (int mi = 0; mi < 4; ++mi) {
        const int off = SWZ_OFF(wm + mi * 16 + r16, s * 4 + kg);
        aA[mi] = *(const half8*)(sA1 + off);
        if (EPI == 2) aB[mi] = *(const half8*)(sA2 + off);
      }
#pragma unroll
      for (int nj = 0; nj < 4; ++nj) {
        const int off = SWZ_OFF(wn + nj * 16 + r16, s * 4 + kg);
        bA[nj] = *(const half8*)(sB1 + off);
        bB[nj] = *(const half8*)(sB2 + off);
      }
#pragma unroll
      for (int mi = 0; mi < 4; ++mi)
#pragma unroll
        for (int nj = 0; nj < 4; ++nj) {
          acc[mi][nj] = __builtin_amdgcn_mfma_f32_16x16x32_f16(aA[mi], bA[nj], acc[mi][nj], 0, 0, 0);
          acc[mi][nj] = __builtin_amdgcn_mfma_f32_16x16x32_f16(aA[mi], bB[nj], acc[mi][nj], 0, 0, 0);
          if (EPI == 2)
            acc[mi][nj] = __builtin_amdgcn_mfma_f32_16x16x32_f16(aB[mi], bA[nj], acc[mi][nj], 0, 0, 0);
        }
    }
  }

#pragma unroll
  for (int mi = 0; mi < 4; ++mi)
#pragma unroll
    for (int nj = 0; nj < 4; ++nj) {
      const int col = n0 + wn + nj * 16 + r16;
#pragma unroll
      for (int j = 0; j < 4; ++j) {
        const int rr = m0 + wm + mi * 16 + kg * 4 + j;
        const float v = acc[mi][nj][j] * INV65536;
        if (EPI == 2) {
          // key = floor((s+8)/KCELL), clamped to u16
          const float sv = v + bias[(size_t)(rr & (NNODES - 1)) * NNODES + col];
          const float f = fminf(fmaxf((sv + 8.0f) * 4096.0f, 0.0f), 65535.0f);
          uint16_t* kbase = (uint16_t*)((char*)C + (size_t)rr * 4096 + 2048);
          kbase[col] = (uint16_t)(unsigned)f;
        } else if (EPI == 0) {
          C[(size_t)rr * DD + col] = v + bias[col];
        } else {
          C[(size_t)rr * DD + col] = v + bias[col] + resid[(size_t)rr * DD + col];
        }
      }
    }
}

// =====================================================================
// Top-64 from u16 keys + masked softmax + sparse messages. One wave/row.
// Grid 8192 XCD-swizzled: batch b's 256 blocks share one XCD (V_b L2-resident
// once). USE16: gather V from fp16 shadow (halves L2 gather bytes).
// k64 via 16-iter radix (ballot+popcount). hi: key>=k64+2 (provably in);
// out: key<=k64-2 (provably out); candidates {k64-1,k64,k64+1}: exact
// fp32 recompute from split Q,K; rank (score desc, index asc) = jax.
// =====================================================================
template <bool USE16>
__global__ __launch_bounds__(256) void topk_softmax_msg(float* __restrict__ S,
                                                        const float* __restrict__ V,
                                                        const _Float16* __restrict__ V16,
                                                        const _Float16* __restrict__ Q1,
                                                        const _Float16* __restrict__ Q2,
                                                        const _Float16* __restrict__ K1,
                                                        const _Float16* __restrict__ K2,
                                                        const float* __restrict__ adj,
                                                        _Float16* __restrict__ M1) {
  const int tid = threadIdx.x;
  const int w = tid >> 6, lane = tid & 63;
  // XCD swizzle: batch = (t>>8)*8 + id%8 -> whole batch on one XCD
  const int id = blockIdx.x;            // 0..8191
  const int xcd = id & 7, t = id >> 3;  // t 0..1023
  const int b = (t >> 8) * 8 + xcd;     // batch 0..31
  const int row = b * NNODES + (t & 255) * 4 + w;
  const int m = row & (NNODES - 1);
  float* Srow = S + (size_t)row * NNODES;
  const uint16_t* krow = (const uint16_t*)((const char*)S + (size_t)row * 4096 + 2048);

  __shared__ float2 spair[4][KNB];  // (wgt, idx bits)
  __shared__ int cidxs[4][32];
  __shared__ float cex[4][32];
  __shared__ int csel[4][32];

  if (lane < KNB) spair[w][lane] = make_float2(0.0f, __int_as_float(0));

  // load 16 keys: cols g*512 + lane*8 + e
  const uint4 u0 = *(const uint4*)(krow + lane * 8);
  const uint4 u1 = *(const uint4*)(krow + 512 + lane * 8);
  int k[16];
  {
    const unsigned uu[8] = {u0.x, u0.y, u0.z, u0.w, u1.x, u1.y, u1.z, u1.w};
#pragma unroll
    for (int q = 0; q < 8; ++q) {
      k[q * 2] = (int)(uu[q] & 0xffffu);
      k[q * 2 + 1] = (int)(uu[q] >> 16);
    }
  }
  // k[t] maps to col(t) = (t>>3)*512 + lane*8 + (t&7)  (t ascending = col ascending per lane)

  float st[16];
#pragma unroll
  for (int t2 = 0; t2 < 16; ++t2) st[t2] = fmaf((float)k[t2] + 0.5f, KCELL, -8.0f);

  // radix-select 64th-largest key (16 bits)
  int cur = 0;
#pragma unroll 1
  for (int bit = 15; bit >= 0; --bit) {
    const int cand = cur | (1 << bit);
    int cnt = 0;
#pragma unroll
    for (int t2 = 0; t2 < 16; ++t2) cnt += (int)__popcll(__ballot(k[t2] >= cand));
    if (cnt >= KNB) cur = cand;
  }

  const int kHi = cur + 2;   // key >= kHi  -> provably in top-64
  const int kLo = cur - 1;   // key <  kLo  -> provably out

  const unsigned long long ltmask = (1ull << lane) - 1ull;
  unsigned hm = 0u, cm = 0u;
  int cpos[16];
  int nhi = 0, ncand = 0;
#pragma unroll
  for (int g = 0; g < 2; ++g) {
    bool hiv[8], cdv[8];
    unsigned long long mh[8], mc[8];
#pragma unroll
    for (int e = 0; e < 8; ++e) {
      const int t2 = g * 8 + e;
      hiv[e] = (k[t2] >= kHi);
      cdv[e] = (!hiv[e]) && (k[t2] >= kLo);
      mh[e] = __ballot(hiv[e]);
      mc[e] = __ballot(cdv[e]);
    }
    int below = 0, tot_h = 0, tot_c = 0;
#pragma unroll
    for (int e = 0; e < 8; ++e) {
      below += (int)__popcll(mc[e] & ltmask);
      tot_h += (int)__popcll(mh[e]);
      tot_c += (int)__popcll(mc[e]);
    }
    int own = 0;
#pragma unroll
    for (int e = 0; e < 8; ++e) {
      const int t2 = g * 8 + e;
      cpos[t2] = -1;
      if (hiv[e]) hm |= (1u << t2);
      if (cdv[e]) {
        cm |= (1u << t2);
        const int p = ncand + below + own;
        cpos[t2] = p;
        if (p < 32) cidxs[w][p] = g * 512 + lane * 8 + e;
        ++own;
      }
    }
    nhi += tot_h;
    ncand += tot_c;
  }
  const int need = KNB - nhi;  // >= 1; nhi+ncand >= 64

  unsigned selm;
  if (ncand == need) {
    selm = hm | cm;  // fast path
  } else {
    const int nc = (ncand <= 32) ? ncand : 32;
    const int nd = (need <= nc) ? need : nc;
    const size_t qoff = (size_t)row * DD + lane * 4;
    const half4 q1v = *(const half4*)(Q1 + qoff);
    const half4 q2v = *(const half4*)(Q2 + qoff);
    float qf[4];
#pragma unroll
    for (int e = 0; e < 4; ++e) qf[e] = (float)q1v[e] + (float)q2v[e];
    const float* adjrow = adj + (size_t)m * NNODES;
#pragma unroll 1
    for (int t2 = 0; t2 < nc; ++t2) {
      const int j = cidxs[w][t2];
      const size_t koff = ((size_t)b * NNODES + j) * DD + lane * 4;
      const half4 k1v = *(const half4*)(K1 + koff);
      const half4 k2v = *(const half4*)(K2 + koff);
      float part = 0.0f;
#pragma unroll
      for (int e = 0; e < 4; ++e) part = fmaf(qf[e], (float)k1v[e] + (float)k2v[e], part);
#pragma unroll
      for (int off = 32; off > 0; off >>= 1) part += __shfl_xor(part, off);
      if (lane == 0) cex[w][t2] = part * INV65536 + adjrow[j];
    }
    if (lane < nc) {
      const float et = cex[w][lane];
      int rank = 0;
      for (int u = 0; u < nc; ++u) {
        const float eu = cex[w][u];
        rank += (eu > et || (eu == et && u < lane)) ? 1 : 0;
      }
      csel[w][lane] = (rank < nd) ? 1 : 0;
    }
    selm = hm;
#pragma unroll
    for (int t2 = 0; t2 < 16; ++t2) {
      if (((cm >> t2) & 1u) && cpos[t2] >= 0 && cpos[t2] < 32 && csel[w][cpos[t2]]) selm |= (1u << t2);
    }
  }

  // softmax over selected (rmax over all; the max element is hi|cand)
  float rmax = st[0];
#pragma unroll
  for (int t2 = 1; t2 < 16; ++t2) rmax = fmaxf(rmax, st[t2]);
#pragma unroll
  for (int off = 32; off > 0; off >>= 1) rmax = fmaxf(rmax, __shfl_xor(rmax, off));

  float p[16];
  float sum = 0.0f;
#pragma unroll
  for (int t2 = 0; t2 < 16; ++t2) {
    p[t2] = __expf(st[t2] - rmax);
    if ((selm >> t2) & 1u) sum += p[t2];
  }
#pragma unroll
  for (int off = 32; off > 0; off >>= 1) sum += __shfl_xor(sum, off);
  const float inv = 1.0f / sum;

  // attn write (overwrites full 4KB row incl. key half) + ordered compaction
  int run = 0;
#pragma unroll
  for (int g = 0; g < 2; ++g) {
    bool sel8[8];
    unsigned long long ms[8];
#pragma unroll
    for (int e = 0; e < 8; ++e) {
      sel8[e] = (selm >> (g * 8 + e)) & 1u;
      ms[e] = __ballot(sel8[e]);
    }
    int below = 0, tot = 0;
#pragma unroll
    for (int e = 0; e < 8; ++e) {
      below += (int)__popcll(ms[e] & ltmask);
      tot += (int)__popcll(ms[e]);
    }
    float ow[8];
    int own = 0;
#pragma unroll
    for (int e = 0; e < 8; ++e) {
      const int t2 = g * 8 + e;
      const float aw = sel8[e] ? p[t2] * inv : 0.0f;
      ow[e] = aw;
      if (sel8[e]) {
        const int pos = run + below + own;
        if (pos < KNB) spair[w][pos] = make_float2(aw, __int_as_float(g * 512 + lane * 8 + e));
        ++own;
      }
    }
    float* dst = Srow + g * 512 + lane * 8;
    *(float4*)(dst) = make_float4(ow[0], ow[1], ow[2], ow[3]);
    *(float4*)(dst + 4) = make_float4(ow[4], ow[5], ow[6], ow[7]);
    run += tot;
  }

  // messages: lane owns output dims [lane*4, lane*4+4)
  float4 acc = {0.0f, 0.0f, 0.0f, 0.0f};
  if (USE16) {
    const _Float16* Vb = V16 + (size_t)b * NNODES * DD;
#pragma unroll 4
    for (int t2 = 0; t2 < KNB; ++t2) {
      const float2 pr = spair[w][t2];
      const int j = __float_as_int(pr.y);
      const half4 vv = *(const half4*)(Vb + (size_t)j * DD + lane * 4);
      acc.x = fmaf(pr.x, (float)vv[0], acc.x);
      acc.y = fmaf(pr.x, (float)vv[1], acc.y);
      acc.z = fmaf(pr.x, (float)vv[2], acc.z);
      acc.w = fmaf(pr.x, (float)vv[3], acc.w);
    }
  } else {
    const float* Vb = V + (size_t)b * NNODES * DD;
#pragma unroll 2
    for (int t2 = 0; t2 < KNB; ++t2) {
      const float2 pr = spair[w][t2];
      const int j = __float_as_int(pr.y);
      const float4 vv = *(const float4*)(Vb + (size_t)j * DD + lane * 4);
      acc.x = fmaf(pr.x, vv.x, acc.x);
      acc.y = fmaf(pr.x, vv.y, acc.y);
      acc.z = fmaf(pr.x, vv.z, acc.z);
      acc.w = fmaf(pr.x, vv.w, acc.w);
    }
  }
  // M stored as single fp16(64*m) -- downstream w1 runs 2-product (A1 only)
  half4 m1;
  m1[0] = (_Float16)(acc.x * 64.0f);
  m1[1] = (_Float16)(acc.y * 64.0f);
  m1[2] = (_Float16)(acc.z * 64.0f);
  m1[3] = (_Float16)(acc.w * 64.0f);
  *(half4*)(M1 + (size_t)row * DD + lane * 4) = m1;
}

// =====================================================================
// LayerNorm + ReLU: H fp32 -> single fp16(64*y).
// =====================================================================
__global__ __launch_bounds__(256) void ln_relu(const float* __restrict__ H,
                                               const float* __restrict__ g,
                                               const float* __restrict__ bta,
                                               _Float16* __restrict__ H1) {
  const int row = blockIdx.x;
  const int c = threadIdx.x;
  const int wv = c >> 6, ln = c & 63;
  const float h = H[(size_t)row * DD + c];

  __shared__ float part[4], part2[4];
  float v = h;
#pragma unroll
  for (int off = 32; off > 0; off >>= 1) v += __shfl_xor(v, off);
  if (ln == 0) part[wv] = v;
  __syncthreads();
  const float mu = (part[0] + part[1] + part[2] + part[3]) * (1.0f / 256.0f);

  const float d = h - mu;
  float sq = d * d;
#pragma unroll
  for (int off = 32; off > 0; off >>= 1) sq += __shfl_xor(sq, off);
  if (ln == 0) part2[wv] = sq;
  __syncthreads();
  const float var = (part2[0] + part2[1] + part2[2] + part2[3]) * (1.0f / 256.0f);

  const float y = fmaxf(d * (1.0f / sqrtf(var + 1e-5f)) * g[c] + bta[c], 0.0f);
  H1[(size_t)row * DD + c] = (_Float16)(y * 64.0f);
}

// =====================================================================
// Host launch
// =====================================================================
extern "C" void kernel_launch(void* const* d_in, const int* in_sizes, int n_in,
                              void* d_out, int out_size, void* d_ws, size_t ws_size,
                              hipStream_t stream) {
  (void)in_sizes; (void)n_in; (void)out_size;
  const float* x   = (const float*)d_in[0];
  const float* wq  = (const float*)d_in[1];
  const float* bq  = (const float*)d_in[2];
  const float* wk  = (const float*)d_in[3];
  const float* bk  = (const float*)d_in[4];
  const float* wv  = (const float*)d_in[5];
  const float* bv  = (const float*)d_in[6];
  const float* adj = (const float*)d_in[7];
  const float* w1  = (const float*)d_in[8];
  const float* b1  = (const float*)d_in[9];
  const float* lng = (const float*)d_in[10];
  const float* lnb = (const float*)d_in[11];
  const float* w2  = (const float*)d_in[12];
  const float* b2  = (const float*)d_in[13];

  const size_t BND = (size_t)MTOT * DD;  // 8,388,608
  float* outp  = (float*)d_out;          // [MTOT][256] (holds V until w2 overwrites)
  float* attnp = outp + BND;             // [MTOT][1024] (X splits -> keys+attn)
  float* V = outp;

  // X1/X2 live in the attn scratch region (dead before scores writes keys)
  _Float16* X1 = (_Float16*)attnp;
  _Float16* X2 = X1 + BND;

  _Float16* Q1 = (_Float16*)d_ws;
  _Float16* Q2 = Q1 + BND;
  _Float16* K1 = Q2 + BND;
  _Float16* K2 = K1 + BND;
  _Float16* WT = K2 + BND;          // [5][2][65536]
  _Float16* V16p = WT + 5 * 131072; // optional fp16 V shadow (16.78 MB)
  const size_t need16 = (size_t)(V16p + BND - (_Float16*)d_ws) * sizeof(_Float16);
  const bool use16 = (ws_size >= need16);
  _Float16* V16 = use16 ? V16p : nullptr;

  _Float16* M1 = Q1;        // reuse after topk (wave reads own Q row first)
  float* H = (float*)K1;    // reuse K region after topk
  _Float16* H1 = Q1;        // reuse after w1 consumed M1

  const dim3 blk(256);

  prep_w<<<dim3(1280), blk, 0, stream>>>(wq, wk, wv, w1, w2, WT);
  prep_x<<<dim3(4096), blk, 0, stream>>>(x, X1, X2);
  gemm_qkv<<<dim3(1536), blk, 0, stream>>>(X1, X2, WT, bq, bk, bv, Q1, Q2, K1, K2, V, V16);
  gemm_split<2><<<dim3(8, 256), blk, 0, stream>>>(Q1, Q2, K1, K2, adj, nullptr, attnp);
  if (use16) {
    topk_softmax_msg<true><<<dim3(MTOT / 4), blk, 0, stream>>>(attnp, V, V16, Q1, Q2, K1, K2, adj, M1);
  } else {
    topk_softmax_msg<false><<<dim3(MTOT / 4), blk, 0, stream>>>(attnp, V, nullptr, Q1, Q2, K1, K2, adj, M1);
  }
  gemm_split<0><<<dim3(2, 256), blk, 0, stream>>>(M1, nullptr, WT + 3 * 131072,
                                                  WT + 3 * 131072 + 65536, b1, nullptr, H);
  ln_relu<<<dim3(MTOT), blk, 0, stream>>>(H, lng, lnb, H1);
  gemm_split<1><<<dim3(2, 256), blk, 0, stream>>>(H1, nullptr, WT + 4 * 131072,
                                                  WT + 4 * 131072 + 65536, b2, V, outp);
}

// Round 9
// 333.756 us; speedup vs baseline: 1.4638x; 1.0146x over previous
//
#include <hip/hip_runtime.h>
#include <cstdint>

#define NB 32
#define NNODES 1024
#define DD 256
#define KNB 64
#define MTOT (NB * NNODES)  // 32768

// Scaling: activations stored as split(64*a), weights as split(1024*w).
// acc = sum (64a)(1024w) = 65536 * a.w  -> epilogue * 1/65536.
// scores acc = (64q).(64k) = 4096 q.k -> q.k/16 = acc/65536 too.
#define INV65536 1.52587890625e-05f
// 16-bit key cell over [-8,8)
#define KCELL 2.44140625e-4f

typedef _Float16 half8 __attribute__((ext_vector_type(8)));
typedef _Float16 half4 __attribute__((ext_vector_type(4)));
typedef float f32x4 __attribute__((ext_vector_type(4)));

typedef __attribute__((address_space(3))) uint32_t lds_u32;
typedef __attribute__((address_space(1))) uint32_t glb_u32;

// 16B async global->LDS. LDS dest wave-uniform; HW adds lane*16.
__device__ __forceinline__ void gll16(const _Float16* g, _Float16* l) {
  __builtin_amdgcn_global_load_lds((const glb_u32*)g, (lds_u32*)l, 16, 0, 0);
}

__device__ __forceinline__ void split2(float v, _Float16& h, _Float16& l) {
  h = (_Float16)v;
  l = (_Float16)(v - (float)h);
}

// =====================================================================
// prep_w: W[k][n] fp32 -> W_T[n][k] fp16x2, scaled by 1024.
// =====================================================================
__global__ __launch_bounds__(256) void prep_w(const float* __restrict__ wq,
                                              const float* __restrict__ wk,
                                              const float* __restrict__ wv,
                                              const float* __restrict__ w1,
                                              const float* __restrict__ w2,
                                              _Float16* __restrict__ WT) {
  const int idx = blockIdx.x * 256 + threadIdx.x;  // < 5*65536
  const int wsel = idx >> 16;
  const int rem = idx & 65535;
  const int k = rem >> 8, n = rem & 255;
  const float* src = (wsel == 0) ? wq : (wsel == 1) ? wk : (wsel == 2) ? wv : (wsel == 3) ? w1 : w2;
  const float v = src[rem] * 1024.0f;
  _Float16 h1, h2;
  split2(v, h1, h2);
  WT[(size_t)wsel * 131072 + n * 256 + k] = h1;
  WT[(size_t)wsel * 131072 + 65536 + n * 256 + k] = h2;
}

// =====================================================================
// prep_x: x fp32 -> X1,X2 = split(64*x) fp16. 8 elems/thread, coalesced.
// =====================================================================
__global__ __launch_bounds__(256) void prep_x(const float* __restrict__ x,
                                              _Float16* __restrict__ X1,
                                              _Float16* __restrict__ X2) {
  const size_t i = ((size_t)blockIdx.x * 256 + threadIdx.x) * 8;
  const float4 a = *(const float4*)(x + i);
  const float4 bb = *(const float4*)(x + i + 4);
  const float vals[8] = {a.x, a.y, a.z, a.w, bb.x, bb.y, bb.z, bb.w};
  half8 h, l;
#pragma unroll
  for (int e = 0; e < 8; ++e) {
    _Float16 hh, ll;
    split2(vals[e] * 64.0f, hh, ll);
    h[e] = hh;
    l[e] = ll;
  }
  *(half8*)(X1 + i) = h;
  *(half8*)(X2 + i) = l;
}

// LDS tile layout: [128 rows][8 chunks of 8 halfs], chunk XOR-swizzled by (row&7)
#define SWZ_OFF(r, cc) ((r) * 64 + (((cc) ^ ((r)&7)) << 3))

// =====================================================================
// gemm_qkv: A=X1/X2 pre-split, B=WT, all via global_load_lds.
// Q,K: 3 products (selection-critical). V: 1 product -> fp16 only
// (residual + gather both read V16; 5e-4 quant << 0.079 tolerance).
// Grid 1D 1536, XCD-swizzled: 6 sibling blocks (same m-rows) per XCD.
// =====================================================================
__global__ __launch_bounds__(256) void gemm_qkv(const _Float16* __restrict__ X1,
                                                const _Float16* __restrict__ X2,
                                                const _Float16* __restrict__ WT,
                                                const float* __restrict__ bq,
                                                const float* __restrict__ bk,
                                                const float* __restrict__ bv,
                                                _Float16* __restrict__ Q1, _Float16* __restrict__ Q2,
                                                _Float16* __restrict__ K1, _Float16* __restrict__ K2,
                                                _Float16* __restrict__ V16) {
  __shared__ _Float16 sm[4 * 8192];
  _Float16* sA1 = sm;
  _Float16* sA2 = sm + 8192;
  _Float16* sB1 = sm + 16384;
  _Float16* sB2 = sm + 24576;

  const int tid = threadIdx.x;
  const int lane = tid & 63, w = tid >> 6;
  const int r16 = lane & 15, kg = lane >> 4;
  const int rsub = lane >> 3, csub = lane & 7;
  const int wm = (w >> 1) * 64, wn = (w & 1) * 64;

  // XCD swizzle: id%8 = XCD; 6 siblings (j=0..5) of each m-tile share id%8
  const int id = blockIdx.x;
  const int c8 = id & 7, t = id >> 3;   // t in 0..191
  const int gy = (t / 6) * 8 + c8;      // m-tile 0..255
  const int j6 = t % 6;
  const int wsel = j6 >> 1;
  const int n0 = (j6 & 1) * 128;
  const int m0 = gy * 128;
  const bool full = (wsel != 2);  // Q,K need 3 products; V needs 1

  const _Float16* pB1 = WT + (size_t)wsel * 131072;
  const _Float16* pB2 = pB1 + 65536;

  f32x4 acc[4][4];
#pragma unroll
  for (int i = 0; i < 4; ++i)
#pragma unroll
    for (int j = 0; j < 4; ++j) acc[i][j] = f32x4{0.f, 0.f, 0.f, 0.f};

  for (int k0 = 0; k0 < DD; k0 += 64) {
    __syncthreads();
#pragma unroll
    for (int it = 0; it < 4; ++it) {
      const int r = (w << 5) + (it << 3) + rsub;
      const int swz = ((csub ^ (r & 7)) << 3);
      const int ldso = (w << 11) + (it << 9);
      gll16(X1 + (size_t)(m0 + r) * DD + k0 + swz, sA1 + ldso);
      gll16(pB1 + (size_t)(n0 + r) * DD + k0 + swz, sB1 + ldso);
      if (full) {
        gll16(X2 + (size_t)(m0 + r) * DD + k0 + swz, sA2 + ldso);
        gll16(pB2 + (size_t)(n0 + r) * DD + k0 + swz, sB2 + ldso);
      }
    }
    __syncthreads();

#pragma unroll
    for (int s = 0; s < 2; ++s) {
      half8 aA[4], aB[4], bA[4], bB[4];
#pragma unroll
      for (int mi = 0; mi < 4; ++mi) {
        const int off = SWZ_OFF(wm + mi * 16 + r16, s * 4 + kg);
        aA[mi] = *(const half8*)(sA1 + off);
      }
#pragma unroll
      for (int nj = 0; nj < 4; ++nj) {
        const int off = SWZ_OFF(wn + nj * 16 + r16, s * 4 + kg);
        bA[nj] = *(const half8*)(sB1 + off);
      }
      if (full) {
#pragma unroll
        for (int mi = 0; mi < 4; ++mi) {
          const int off = SWZ_OFF(wm + mi * 16 + r16, s * 4 + kg);
          aB[mi] = *(const half8*)(sA2 + off);
        }
#pragma unroll
        for (int nj = 0; nj < 4; ++nj) {
          const int off = SWZ_OFF(wn + nj * 16 + r16, s * 4 + kg);
          bB[nj] = *(const half8*)(sB2 + off);
        }
      }
#pragma unroll
      for (int mi = 0; mi < 4; ++mi)
#pragma unroll
        for (int nj = 0; nj < 4; ++nj) {
          acc[mi][nj] = __builtin_amdgcn_mfma_f32_16x16x32_f16(aA[mi], bA[nj], acc[mi][nj], 0, 0, 0);
          if (full) {
            acc[mi][nj] = __builtin_amdgcn_mfma_f32_16x16x32_f16(aA[mi], bB[nj], acc[mi][nj], 0, 0, 0);
            acc[mi][nj] = __builtin_amdgcn_mfma_f32_16x16x32_f16(aB[mi], bA[nj], acc[mi][nj], 0, 0, 0);
          }
        }
    }
  }

  const float* bsel = (wsel == 0) ? bq : (wsel == 1) ? bk : bv;
  _Float16* P1 = (wsel == 0) ? Q1 : K1;
  _Float16* P2 = (wsel == 0) ? Q2 : K2;
#pragma unroll
  for (int mi = 0; mi < 4; ++mi)
#pragma unroll
    for (int nj = 0; nj < 4; ++nj) {
      const int col = n0 + wn + nj * 16 + r16;
#pragma unroll
      for (int j = 0; j < 4; ++j) {
        const int rr = m0 + wm + mi * 16 + kg * 4 + j;
        if (wsel == 2) {
          V16[(size_t)rr * DD + col] = (_Float16)(acc[mi][nj][j] * INV65536 + bsel[col]);
        } else {
          // store 64*Q = acc/1024 + 64*bias
          const float qv = acc[mi][nj][j] * (1.0f / 1024.0f) + 64.0f * bsel[col];
          _Float16 h1, h2;
          split2(qv, h1, h2);
          P1[(size_t)rr * DD + col] = h1;
          P2[(size_t)rr * DD + col] = h2;
        }
      }
    }
}

// =====================================================================
// gemm_split<EPI>: A,B pre-split fp16x2, K-major rows (NT).
// EPI 0: C = acc/65536 + bias              (w1 -> H fp32), 2 products
// EPI 1: C = acc/65536 + bias + resid16    (w2 -> out),    2 products
// EPI 2: scores -> u16 keys (bytes 2048..4095 of each attn row's 4KB),
//        2 products (Q_hi.K_hi + Q_hi.K_lo; dropped Q_lo.K term covered
//        by topk's +-16-cell candidate band + exact recompute).
// =====================================================================
template <int EPI>
__global__ __launch_bounds__(256) void gemm_split(const _Float16* __restrict__ A1,
                                                  const _Float16* __restrict__ B1g,
                                                  const _Float16* __restrict__ B2g,
                                                  const float* __restrict__ bias,
                                                  const _Float16* __restrict__ resid16,
                                                  float* __restrict__ C) {
  __shared__ _Float16 sm[3 * 8192];
  _Float16* sA1 = sm;
  _Float16* sB1 = sm + 8192;
  _Float16* sB2 = sm + 16384;

  const int tid = threadIdx.x;
  const int lane = tid & 63, w = tid >> 6;
  const int r16 = lane & 15, kg = lane >> 4;
  const int rsub = lane >> 3, csub = lane & 7;
  const int wm = (w >> 1) * 64, wn = (w & 1) * 64;

  const int n0 = blockIdx.x * 128;
  const int m0 = blockIdx.y * 128;

  const _Float16* pB1 = B1g;
  const _Float16* pB2 = B2g;
  if (EPI == 2) {
    const size_t boff = (size_t)(m0 >> 10) * NNODES * DD;
    pB1 += boff;
    pB2 += boff;
  }

  f32x4 acc[4][4];
#pragma unroll
  for (int i = 0; i < 4; ++i)
#pragma unroll
    for (int j = 0; j < 4; ++j) acc[i][j] = f32x4{0.f, 0.f, 0.f, 0.f};

  for (int k0 = 0; k0 < DD; k0 += 64) {
    __syncthreads();
#pragma unroll
    for (int it = 0; it < 4; ++it) {
      const int r = (w << 5) + (it << 3) + rsub;
      const int swz = ((csub ^ (r & 7)) << 3);
      const int ldso = (w << 11) + (it << 9);
      gll16(A1 + (size_t)(m0 + r) * DD + k0 + swz, sA1 + ldso);
      gll16(pB1 + (size_t)(n0 + r) * DD + k0 + swz, sB1 + ldso);
      gll16(pB2 + (size_t)(n0 + r) * DD + k0 + swz, sB2 + ldso);
    }
    __syncthreads();

#pragma unroll
    for (int s = 0; s < 2; ++s) {
      half8 aA[4], bA[4], bB[4];
#pragma unroll
      for (int mi = 0; mi < 4; ++mi) {
        const int off = SWZ_OFF(wm + mi * 16 + r16, s * 4 + kg);
        aA[mi] = *(const half8*)(sA1 + off);
      }
#pragma unroll
      for (int nj = 0; nj < 4; ++nj) {
        const int off = SWZ_OFF(wn + nj * 16 + r16, s * 4 + kg);
        bA[nj] = *(const half8*)(sB1 + off);
        bB[nj] = *(const half8*)(sB2 + off);
      }
#pragma unroll
      for (int mi = 0; mi < 4; ++mi)
#pragma unroll
        for (int nj = 0; nj < 4; ++nj) {
          acc[mi][nj] = __builtin_amdgcn_mfma_f32_16x16x32_f16(aA[mi], bA[nj], acc[mi][nj], 0, 0, 0);
          acc[mi][nj] = __builtin_amdgcn_mfma_f32_16x16x32_f16(aA[mi], bB[nj], acc[mi][nj], 0, 0, 0);
        }
    }
  }

#pragma unroll
  for (int mi = 0; mi < 4; ++mi)
#pragma unroll
    for (int nj = 0; nj < 4; ++nj) {
      const int col = n0 + wn + nj * 16 + r16;
#pragma unroll
      for (int j = 0; j < 4; ++j) {
        const int rr = m0 + wm + mi * 16 + kg * 4 + j;
        const float v = acc[mi][nj][j] * INV65536;
        if (EPI == 2) {
          const float sv = v + bias[(size_t)(rr & (NNODES - 1)) * NNODES + col];
          const float f = fminf(fmaxf((sv + 8.0f) * 4096.0f, 0.0f), 65535.0f);
          uint16_t* kbase = (uint16_t*)((char*)C + (size_t)rr * 4096 + 2048);
          kbase[col] = (uint16_t)(unsigned)f;
        } else if (EPI == 0) {
          C[(size_t)rr * DD + col] = v + bias[col];
        } else {
          C[(size_t)rr * DD + col] = v + bias[col] + (float)resid16[(size_t)rr * DD + col];
        }
      }
    }
}

// =====================================================================
// Top-64 from u16 keys + masked softmax + sparse messages. One wave/row.
// __launch_bounds__(256,4): 128-VGPR cap so k/st/p arrays stay in regs
// (r8's 32-VGPR squeeze caused massive rematerialization -> VALU-bound).
// Band: hi key>=cur+17 (provably in), out key<=cur-17 (provably out) --
// covers the 2-product score error (<=8 cells incl. order-stat shift).
// Candidates: exact fp32 recompute from split Q,K; jax tie semantics.
// =====================================================================
__global__ __launch_bounds__(256, 4) void topk_softmax_msg(float* __restrict__ S,
                                                           const _Float16* __restrict__ V16,
                                                           const _Float16* __restrict__ Q1,
                                                           const _Float16* __restrict__ Q2,
                                                           const _Float16* __restrict__ K1,
                                                           const _Float16* __restrict__ K2,
                                                           const float* __restrict__ adj,
                                                           _Float16* __restrict__ M1) {
  const int tid = threadIdx.x;
  const int w = tid >> 6, lane = tid & 63;
  // XCD swizzle: batch = (t>>8)*8 + id%8 -> whole batch on one XCD
  const int id = blockIdx.x;            // 0..8191
  const int xcd = id & 7, t = id >> 3;  // t 0..1023
  const int b = (t >> 8) * 8 + xcd;     // batch 0..31
  const int row = b * NNODES + (t & 255) * 4 + w;
  const int m = row & (NNODES - 1);
  float* Srow = S + (size_t)row * NNODES;
  const uint16_t* krow = (const uint16_t*)((const char*)S + (size_t)row * 4096 + 2048);

  __shared__ float2 spair[4][KNB];  // (wgt, V16 row byte-offset bits)
  __shared__ int cidxs[4][32];
  __shared__ float cex[4][32];
  __shared__ int csel[4][32];

  if (lane < KNB) spair[w][lane] = make_float2(0.0f, __int_as_float(0));

  // load 16 keys: cols g*512 + lane*8 + e
  const uint4 u0 = *(const uint4*)(krow + lane * 8);
  const uint4 u1 = *(const uint4*)(krow + 512 + lane * 8);
  int k[16];
  {
    const unsigned uu[8] = {u0.x, u0.y, u0.z, u0.w, u1.x, u1.y, u1.z, u1.w};
#pragma unroll
    for (int q = 0; q < 8; ++q) {
      k[q * 2] = (int)(uu[q] & 0xffffu);
      k[q * 2 + 1] = (int)(uu[q] >> 16);
    }
  }
  // k[t] maps to col(t) = (t>>3)*512 + lane*8 + (t&7)

  float st[16];
#pragma unroll
  for (int t2 = 0; t2 < 16; ++t2) st[t2] = fmaf((float)k[t2] + 0.5f, KCELL, -8.0f);

  // radix-select 64th-largest key (16 bits)
  int cur = 0;
#pragma unroll 1
  for (int bit = 15; bit >= 0; --bit) {
    const int cand = cur | (1 << bit);
    int cnt = 0;
#pragma unroll
    for (int t2 = 0; t2 < 16; ++t2) cnt += (int)__popcll(__ballot(k[t2] >= cand));
    if (cnt >= KNB) cur = cand;
  }

  const int kHi = cur + 17;  // key >= kHi -> provably in top-64
  const int kLo = cur - 16;  // key <  kLo -> provably out

  const unsigned long long ltmask = (1ull << lane) - 1ull;
  unsigned hm = 0u, cm = 0u;
  int cpos[16];
  int nhi = 0, ncand = 0;
#pragma unroll
  for (int g = 0; g < 2; ++g) {
    bool hiv[8], cdv[8];
    unsigned long long mh[8], mc[8];
#pragma unroll
    for (int e = 0; e < 8; ++e) {
      const int t2 = g * 8 + e;
      hiv[e] = (k[t2] >= kHi);
      cdv[e] = (!hiv[e]) && (k[t2] >= kLo);
      mh[e] = __ballot(hiv[e]);
      mc[e] = __ballot(cdv[e]);
    }
    int below = 0, tot_h = 0, tot_c = 0;
#pragma unroll
    for (int e = 0; e < 8; ++e) {
      below += (int)__popcll(mc[e] & ltmask);
      tot_h += (int)__popcll(mh[e]);
      tot_c += (int)__popcll(mc[e]);
    }
    int own = 0;
#pragma unroll
    for (int e = 0; e < 8; ++e) {
      const int t2 = g * 8 + e;
      cpos[t2] = -1;
      if (hiv[e]) hm |= (1u << t2);
      if (cdv[e]) {
        cm |= (1u << t2);
        const int p = ncand + below + own;
        cpos[t2] = p;
        if (p < 32) cidxs[w][p] = g * 512 + lane * 8 + e;
        ++own;
      }
    }
    nhi += tot_h;
    ncand += tot_c;
  }
  const int need = KNB - nhi;  // >= 1; nhi+ncand >= 64

  unsigned selm;
  if (ncand == need) {
    selm = hm | cm;  // fast path
  } else {
    const int nc = (ncand <= 32) ? ncand : 32;
    const int nd = (need <= nc) ? need : nc;
    const size_t qoff = (size_t)row * DD + lane * 4;
    const half4 q1v = *(const half4*)(Q1 + qoff);
    const half4 q2v = *(const half4*)(Q2 + qoff);
    float qf[4];
#pragma unroll
    for (int e = 0; e < 4; ++e) qf[e] = (float)q1v[e] + (float)q2v[e];
    const float* adjrow = adj + (size_t)m * NNODES;
#pragma unroll 1
    for (int t2 = 0; t2 < nc; ++t2) {
      const int j = cidxs[w][t2];
      const size_t koff = ((size_t)b * NNODES + j) * DD + lane * 4;
      const half4 k1v = *(const half4*)(K1 + koff);
      const half4 k2v = *(const half4*)(K2 + koff);
      float part = 0.0f;
#pragma unroll
      for (int e = 0; e < 4; ++e) part = fmaf(qf[e], (float)k1v[e] + (float)k2v[e], part);
#pragma unroll
      for (int off = 32; off > 0; off >>= 1) part += __shfl_xor(part, off);
      if (lane == 0) cex[w][t2] = part * INV65536 + adjrow[j];
    }
    if (lane < nc) {
      const float et = cex[w][lane];
      int rank = 0;
      for (int u = 0; u < nc; ++u) {
        const float eu = cex[w][u];
        rank += (eu > et || (eu == et && u < lane)) ? 1 : 0;
      }
      csel[w][lane] = (rank < nd) ? 1 : 0;
    }
    selm = hm;
#pragma unroll
    for (int t2 = 0; t2 < 16; ++t2) {
      if (((cm >> t2) & 1u) && cpos[t2] >= 0 && cpos[t2] < 32 && csel[w][cpos[t2]]) selm |= (1u << t2);
    }
  }

  // softmax over selected (rmax over all; the max element is hi|cand)
  float rmax = st[0];
#pragma unroll
  for (int t2 = 1; t2 < 16; ++t2) rmax = fmaxf(rmax, st[t2]);
#pragma unroll
  for (int off = 32; off > 0; off >>= 1) rmax = fmaxf(rmax, __shfl_xor(rmax, off));

  float p[16];
  float sum = 0.0f;
#pragma unroll
  for (int t2 = 0; t2 < 16; ++t2) {
    p[t2] = __expf(st[t2] - rmax);
    if ((selm >> t2) & 1u) sum += p[t2];
  }
#pragma unroll
  for (int off = 32; off > 0; off >>= 1) sum += __shfl_xor(sum, off);
  const float inv = 1.0f / sum;

  // attn write (overwrites full 4KB row incl. key half) + ordered compaction
  int run = 0;
#pragma unroll
  for (int g = 0; g < 2; ++g) {
    bool sel8[8];
    unsigned long long ms[8];
#pragma unroll
    for (int e = 0; e < 8; ++e) {
      sel8[e] = (selm >> (g * 8 + e)) & 1u;
      ms[e] = __ballot(sel8[e]);
    }
    int below = 0, tot = 0;
#pragma unroll
    for (int e = 0; e < 8; ++e) {
      below += (int)__popcll(ms[e] & ltmask);
      tot += (int)__popcll(ms[e]);
    }
    float ow[8];
    int own = 0;
#pragma unroll
    for (int e = 0; e < 8; ++e) {
      const int t2 = g * 8 + e;
      const float aw = sel8[e] ? p[t2] * inv : 0.0f;
      ow[e] = aw;
      if (sel8[e]) {
        const int pos = run + below + own;
        // store V16 row byte-offset: col * DD * 2
        if (pos < KNB)
          spair[w][pos] = make_float2(aw, __int_as_float((g * 512 + lane * 8 + e) * (DD * 2)));
        ++own;
      }
    }
    float* dst = Srow + g * 512 + lane * 8;
    *(float4*)(dst) = make_float4(ow[0], ow[1], ow[2], ow[3]);
    *(float4*)(dst + 4) = make_float4(ow[4], ow[5], ow[6], ow[7]);
    run += tot;
  }

  // messages: lane owns output dims [lane*4, lane*4+4)
  float4 acc = {0.0f, 0.0f, 0.0f, 0.0f};
  const char* Vbase = (const char*)(V16 + (size_t)b * NNODES * DD) + lane * 8;
#pragma unroll 4
  for (int t2 = 0; t2 < KNB; ++t2) {
    const float2 pr = spair[w][t2];
    const int off = __float_as_int(pr.y);
    const half4 vv = *(const half4*)(Vbase + off);
    acc.x = fmaf(pr.x, (float)vv[0], acc.x);
    acc.y = fmaf(pr.x, (float)vv[1], acc.y);
    acc.z = fmaf(pr.x, (float)vv[2], acc.z);
    acc.w = fmaf(pr.x, (float)vv[3], acc.w);
  }
  // M stored as single fp16(64*m) -- downstream w1 runs 2-product
  half4 m1;
  m1[0] = (_Float16)(acc.x * 64.0f);
  m1[1] = (_Float16)(acc.y * 64.0f);
  m1[2] = (_Float16)(acc.z * 64.0f);
  m1[3] = (_Float16)(acc.w * 64.0f);
  *(half4*)(M1 + (size_t)row * DD + lane * 4) = m1;
}

// =====================================================================
// LayerNorm + ReLU: H fp32 -> single fp16(64*y).
// =====================================================================
__global__ __launch_bounds__(256) void ln_relu(const float* __restrict__ H,
                                               const float* __restrict__ g,
                                               const float* __restrict__ bta,
                                               _Float16* __restrict__ H1) {
  const int row = blockIdx.x;
  const int c = threadIdx.x;
  const int wv = c >> 6, ln = c & 63;
  const float h = H[(size_t)row * DD + c];

  __shared__ float part[4], part2[4];
  float v = h;
#pragma unroll
  for (int off = 32; off > 0; off >>= 1) v += __shfl_xor(v, off);
  if (ln == 0) part[wv] = v;
  __syncthreads();
  const float mu = (part[0] + part[1] + part[2] + part[3]) * (1.0f / 256.0f);

  const float d = h - mu;
  float sq = d * d;
#pragma unroll
  for (int off = 32; off > 0; off >>= 1) sq += __shfl_xor(sq, off);
  if (ln == 0) part2[wv] = sq;
  __syncthreads();
  const float var = (part2[0] + part2[1] + part2[2] + part2[3]) * (1.0f / 256.0f);

  const float y = fmaxf(d * (1.0f / sqrtf(var + 1e-5f)) * g[c] + bta[c], 0.0f);
  H1[(size_t)row * DD + c] = (_Float16)(y * 64.0f);
}

// =====================================================================
// Host launch
// =====================================================================
extern "C" void kernel_launch(void* const* d_in, const int* in_sizes, int n_in,
                              void* d_out, int out_size, void* d_ws, size_t ws_size,
                              hipStream_t stream) {
  (void)in_sizes; (void)n_in; (void)out_size; (void)ws_size;
  const float* x   = (const float*)d_in[0];
  const float* wq  = (const float*)d_in[1];
  const float* bq  = (const float*)d_in[2];
  const float* wk  = (const float*)d_in[3];
  const float* bk  = (const float*)d_in[4];
  const float* wv  = (const float*)d_in[5];
  const float* bv  = (const float*)d_in[6];
  const float* adj = (const float*)d_in[7];
  const float* w1  = (const float*)d_in[8];
  const float* b1  = (const float*)d_in[9];
  const float* lng = (const float*)d_in[10];
  const float* lnb = (const float*)d_in[11];
  const float* w2  = (const float*)d_in[12];
  const float* b2  = (const float*)d_in[13];

  const size_t BND = (size_t)MTOT * DD;  // 8,388,608
  float* outp  = (float*)d_out;          // [MTOT][256] (written by final w2 gemm)
  float* attnp = outp + BND;             // [MTOT][1024] (X splits -> keys+attn)

  // X1/X2 live in the attn scratch region (dead before scores writes keys)
  _Float16* X1 = (_Float16*)attnp;
  _Float16* X2 = X1 + BND;

  _Float16* Q1 = (_Float16*)d_ws;   // ~85 MB total ws use (proven available)
  _Float16* Q2 = Q1 + BND;
  _Float16* K1 = Q2 + BND;
  _Float16* K2 = K1 + BND;
  _Float16* WT = K2 + BND;          // [5][2][65536]
  _Float16* V16 = WT + 5 * 131072;  // fp16 V (16.78 MB)

  _Float16* M1 = Q1;        // reuse after topk (wave reads own Q row first)
  float* H = (float*)K1;    // reuse K region after topk
  _Float16* H1 = Q1;        // reuse after w1 consumed M1

  const dim3 blk(256);

  prep_w<<<dim3(1280), blk, 0, stream>>>(wq, wk, wv, w1, w2, WT);
  prep_x<<<dim3(4096), blk, 0, stream>>>(x, X1, X2);
  gemm_qkv<<<dim3(1536), blk, 0, stream>>>(X1, X2, WT, bq, bk, bv, Q1, Q2, K1, K2, V16);
  gemm_split<2><<<dim3(8, 256), blk, 0, stream>>>(Q1, K1, K2, adj, nullptr, attnp);
  topk_softmax_msg<<<dim3(MTOT / 4), blk, 0, stream>>>(attnp, V16, Q1, Q2, K1, K2, adj, M1);
  gemm_split<0><<<dim3(2, 256), blk, 0, stream>>>(M1, WT + 3 * 131072, WT + 3 * 131072 + 65536,
                                                  b1, nullptr, H);
  ln_relu<<<dim3(MTOT), blk, 0, stream>>>(H, lng, lnb, H1);
  gemm_split<1><<<dim3(2, 256), blk, 0, stream>>>(H1, WT + 4 * 131072, WT + 4 * 131072 + 65536,
                                                  b2, V16, outp);
}

// Round 10
// 304.698 us; speedup vs baseline: 1.6034x; 1.0954x over previous
//
#include <hip/hip_runtime.h>
#include <cstdint>

#define NB 32
#define NNODES 1024
#define DD 256
#define KNB 64
#define MTOT (NB * NNODES)  // 32768

// Scaling: activations stored as split(64*a), weights as split(1024*w).
// acc = sum (64a)(1024w) = 65536 * a.w  -> epilogue * 1/65536.
// scores acc = (64q).(64k) = 4096 q.k -> q.k/16 = acc/65536 too.
#define INV65536 1.52587890625e-05f
// 16-bit key cell over [-8,8)
#define KCELL 2.44140625e-4f

typedef _Float16 half8 __attribute__((ext_vector_type(8)));
typedef _Float16 half4 __attribute__((ext_vector_type(4)));
typedef float f32x4 __attribute__((ext_vector_type(4)));

typedef __attribute__((address_space(3))) uint32_t lds_u32;
typedef __attribute__((address_space(1))) uint32_t glb_u32;

// 16B async global->LDS. LDS dest wave-uniform; HW adds lane*16.
__device__ __forceinline__ void gll16(const _Float16* g, _Float16* l) {
  __builtin_amdgcn_global_load_lds((const glb_u32*)g, (lds_u32*)l, 16, 0, 0);
}

__device__ __forceinline__ void split2(float v, _Float16& h, _Float16& l) {
  h = (_Float16)v;
  l = (_Float16)(v - (float)h);
}

// =====================================================================
// prep_w: W[k][n] fp32 -> W_T[n][k] fp16x2, scaled by 1024.
// =====================================================================
__global__ __launch_bounds__(256) void prep_w(const float* __restrict__ wq,
                                              const float* __restrict__ wk,
                                              const float* __restrict__ wv,
                                              const float* __restrict__ w1,
                                              const float* __restrict__ w2,
                                              _Float16* __restrict__ WT) {
  const int idx = blockIdx.x * 256 + threadIdx.x;  // < 5*65536
  const int wsel = idx >> 16;
  const int rem = idx & 65535;
  const int k = rem >> 8, n = rem & 255;
  const float* src = (wsel == 0) ? wq : (wsel == 1) ? wk : (wsel == 2) ? wv : (wsel == 3) ? w1 : w2;
  const float v = src[rem] * 1024.0f;
  _Float16 h1, h2;
  split2(v, h1, h2);
  WT[(size_t)wsel * 131072 + n * 256 + k] = h1;
  WT[(size_t)wsel * 131072 + 65536 + n * 256 + k] = h2;
}

// =====================================================================
// prep_x: x fp32 -> X1,X2 = split(64*x) fp16. 8 elems/thread, coalesced.
// =====================================================================
__global__ __launch_bounds__(256) void prep_x(const float* __restrict__ x,
                                              _Float16* __restrict__ X1,
                                              _Float16* __restrict__ X2) {
  const size_t i = ((size_t)blockIdx.x * 256 + threadIdx.x) * 8;
  const float4 a = *(const float4*)(x + i);
  const float4 bb = *(const float4*)(x + i + 4);
  const float vals[8] = {a.x, a.y, a.z, a.w, bb.x, bb.y, bb.z, bb.w};
  half8 h, l;
#pragma unroll
  for (int e = 0; e < 8; ++e) {
    _Float16 hh, ll;
    split2(vals[e] * 64.0f, hh, ll);
    h[e] = hh;
    l[e] = ll;
  }
  *(half8*)(X1 + i) = h;
  *(half8*)(X2 + i) = l;
}

// LDS tile layout: [128 rows][8 chunks of 8 halfs], chunk XOR-swizzled by (row&7)
#define SWZ_OFF(r, cc) ((r) * 64 + (((cc) ^ ((r)&7)) << 3))

// =====================================================================
// gemm_qkv: A=X1/X2 pre-split, B=WT, all via global_load_lds.
// Q,K: 3 products (selection-critical). V: 1 product -> fp16 only.
// Grid 1D 1536, XCD-swizzled: 6 sibling blocks (same m-rows) per XCD.
// =====================================================================
__global__ __launch_bounds__(256) void gemm_qkv(const _Float16* __restrict__ X1,
                                                const _Float16* __restrict__ X2,
                                                const _Float16* __restrict__ WT,
                                                const float* __restrict__ bq,
                                                const float* __restrict__ bk,
                                                const float* __restrict__ bv,
                                                _Float16* __restrict__ Q1, _Float16* __restrict__ Q2,
                                                _Float16* __restrict__ K1, _Float16* __restrict__ K2,
                                                _Float16* __restrict__ V16) {
  __shared__ _Float16 sm[4 * 8192];
  _Float16* sA1 = sm;
  _Float16* sA2 = sm + 8192;
  _Float16* sB1 = sm + 16384;
  _Float16* sB2 = sm + 24576;

  const int tid = threadIdx.x;
  const int lane = tid & 63, w = tid >> 6;
  const int r16 = lane & 15, kg = lane >> 4;
  const int rsub = lane >> 3, csub = lane & 7;
  const int wm = (w >> 1) * 64, wn = (w & 1) * 64;

  // XCD swizzle: id%8 = XCD; 6 siblings (j=0..5) of each m-tile share id%8
  const int id = blockIdx.x;
  const int c8 = id & 7, t = id >> 3;   // t in 0..191
  const int gy = (t / 6) * 8 + c8;      // m-tile 0..255
  const int j6 = t % 6;
  const int wsel = j6 >> 1;
  const int n0 = (j6 & 1) * 128;
  const int m0 = gy * 128;
  const bool full = (wsel != 2);  // Q,K need 3 products; V needs 1

  const _Float16* pB1 = WT + (size_t)wsel * 131072;
  const _Float16* pB2 = pB1 + 65536;

  f32x4 acc[4][4];
#pragma unroll
  for (int i = 0; i < 4; ++i)
#pragma unroll
    for (int j = 0; j < 4; ++j) acc[i][j] = f32x4{0.f, 0.f, 0.f, 0.f};

  for (int k0 = 0; k0 < DD; k0 += 64) {
    __syncthreads();
#pragma unroll
    for (int it = 0; it < 4; ++it) {
      const int r = (w << 5) + (it << 3) + rsub;
      const int swz = ((csub ^ (r & 7)) << 3);
      const int ldso = (w << 11) + (it << 9);
      gll16(X1 + (size_t)(m0 + r) * DD + k0 + swz, sA1 + ldso);
      gll16(pB1 + (size_t)(n0 + r) * DD + k0 + swz, sB1 + ldso);
      if (full) {
        gll16(X2 + (size_t)(m0 + r) * DD + k0 + swz, sA2 + ldso);
        gll16(pB2 + (size_t)(n0 + r) * DD + k0 + swz, sB2 + ldso);
      }
    }
    __syncthreads();

#pragma unroll
    for (int s = 0; s < 2; ++s) {
      half8 aA[4], aB[4], bA[4], bB[4];
#pragma unroll
      for (int mi = 0; mi < 4; ++mi) {
        const int off = SWZ_OFF(wm + mi * 16 + r16, s * 4 + kg);
        aA[mi] = *(const half8*)(sA1 + off);
      }
#pragma unroll
      for (int nj = 0; nj < 4; ++nj) {
        const int off = SWZ_OFF(wn + nj * 16 + r16, s * 4 + kg);
        bA[nj] = *(const half8*)(sB1 + off);
      }
      if (full) {
#pragma unroll
        for (int mi = 0; mi < 4; ++mi) {
          const int off = SWZ_OFF(wm + mi * 16 + r16, s * 4 + kg);
          aB[mi] = *(const half8*)(sA2 + off);
        }
#pragma unroll
        for (int nj = 0; nj < 4; ++nj) {
          const int off = SWZ_OFF(wn + nj * 16 + r16, s * 4 + kg);
          bB[nj] = *(const half8*)(sB2 + off);
        }
      }
#pragma unroll
      for (int mi = 0; mi < 4; ++mi)
#pragma unroll
        for (int nj = 0; nj < 4; ++nj) {
          acc[mi][nj] = __builtin_amdgcn_mfma_f32_16x16x32_f16(aA[mi], bA[nj], acc[mi][nj], 0, 0, 0);
          if (full) {
            acc[mi][nj] = __builtin_amdgcn_mfma_f32_16x16x32_f16(aA[mi], bB[nj], acc[mi][nj], 0, 0, 0);
            acc[mi][nj] = __builtin_amdgcn_mfma_f32_16x16x32_f16(aB[mi], bA[nj], acc[mi][nj], 0, 0, 0);
          }
        }
    }
  }

  const float* bsel = (wsel == 0) ? bq : (wsel == 1) ? bk : bv;
  _Float16* P1 = (wsel == 0) ? Q1 : K1;
  _Float16* P2 = (wsel == 0) ? Q2 : K2;
#pragma unroll
  for (int mi = 0; mi < 4; ++mi)
#pragma unroll
    for (int nj = 0; nj < 4; ++nj) {
      const int col = n0 + wn + nj * 16 + r16;
#pragma unroll
      for (int j = 0; j < 4; ++j) {
        const int rr = m0 + wm + mi * 16 + kg * 4 + j;
        if (wsel == 2) {
          V16[(size_t)rr * DD + col] = (_Float16)(acc[mi][nj][j] * INV65536 + bsel[col]);
        } else {
          // store 64*Q = acc/1024 + 64*bias
          const float qv = acc[mi][nj][j] * (1.0f / 1024.0f) + 64.0f * bsel[col];
          _Float16 h1, h2;
          split2(qv, h1, h2);
          P1[(size_t)rr * DD + col] = h1;
          P2[(size_t)rr * DD + col] = h2;
        }
      }
    }
}

// =====================================================================
// gemm_split<EPI>: A single-split fp16, B pre-split fp16x2 (NT).
// EPI 0: H16 = fp16(acc/65536 + bias)      (w1 -> H16), 2 products
// EPI 1: C = acc/65536 + bias + resid16    (w2 -> out), 2 products
// EPI 2: scores -> u16 keys (bytes 2048..4095 of each attn row's 4KB),
//        2 products; dropped Q_lo term covered by topk's +-4-cell band.
// =====================================================================
template <int EPI>
__global__ __launch_bounds__(256) void gemm_split(const _Float16* __restrict__ A1,
                                                  const _Float16* __restrict__ B1g,
                                                  const _Float16* __restrict__ B2g,
                                                  const float* __restrict__ bias,
                                                  const _Float16* __restrict__ resid16,
                                                  float* __restrict__ C,
                                                  _Float16* __restrict__ C16) {
  __shared__ _Float16 sm[3 * 8192];
  _Float16* sA1 = sm;
  _Float16* sB1 = sm + 8192;
  _Float16* sB2 = sm + 16384;

  const int tid = threadIdx.x;
  const int lane = tid & 63, w = tid >> 6;
  const int r16 = lane & 15, kg = lane >> 4;
  const int rsub = lane >> 3, csub = lane & 7;
  const int wm = (w >> 1) * 64, wn = (w & 1) * 64;

  const int n0 = blockIdx.x * 128;
  const int m0 = blockIdx.y * 128;

  const _Float16* pB1 = B1g;
  const _Float16* pB2 = B2g;
  if (EPI == 2) {
    const size_t boff = (size_t)(m0 >> 10) * NNODES * DD;
    pB1 += boff;
    pB2 += boff;
  }

  f32x4 acc[4][4];
#pragma unroll
  for (int i = 0; i < 4; ++i)
#pragma unroll
    for (int j = 0; j < 4; ++j) acc[i][j] = f32x4{0.f, 0.f, 0.f, 0.f};

  for (int k0 = 0; k0 < DD; k0 += 64) {
    __syncthreads();
#pragma unroll
    for (int it = 0; it < 4; ++it) {
      const int r = (w << 5) + (it << 3) + rsub;
      const int swz = ((csub ^ (r & 7)) << 3);
      const int ldso = (w << 11) + (it << 9);
      gll16(A1 + (size_t)(m0 + r) * DD + k0 + swz, sA1 + ldso);
      gll16(pB1 + (size_t)(n0 + r) * DD + k0 + swz, sB1 + ldso);
      gll16(pB2 + (size_t)(n0 + r) * DD + k0 + swz, sB2 + ldso);
    }
    __syncthreads();

#pragma unroll
    for (int s = 0; s < 2; ++s) {
      half8 aA[4], bA[4], bB[4];
#pragma unroll
      for (int mi = 0; mi < 4; ++mi) {
        const int off = SWZ_OFF(wm + mi * 16 + r16, s * 4 + kg);
        aA[mi] = *(const half8*)(sA1 + off);
      }
#pragma unroll
      for (int nj = 0; nj < 4; ++nj) {
        const int off = SWZ_OFF(wn + nj * 16 + r16, s * 4 + kg);
        bA[nj] = *(const half8*)(sB1 + off);
        bB[nj] = *(const half8*)(sB2 + off);
      }
#pragma unroll
      for (int mi = 0; mi < 4; ++mi)
#pragma unroll
        for (int nj = 0; nj < 4; ++nj) {
          acc[mi][nj] = __builtin_amdgcn_mfma_f32_16x16x32_f16(aA[mi], bA[nj], acc[mi][nj], 0, 0, 0);
          acc[mi][nj] = __builtin_amdgcn_mfma_f32_16x16x32_f16(aA[mi], bB[nj], acc[mi][nj], 0, 0, 0);
        }
    }
  }

#pragma unroll
  for (int mi = 0; mi < 4; ++mi)
#pragma unroll
    for (int nj = 0; nj < 4; ++nj) {
      const int col = n0 + wn + nj * 16 + r16;
#pragma unroll
      for (int j = 0; j < 4; ++j) {
        const int rr = m0 + wm + mi * 16 + kg * 4 + j;
        const float v = acc[mi][nj][j] * INV65536;
        if (EPI == 2) {
          const float sv = v + bias[(size_t)(rr & (NNODES - 1)) * NNODES + col];
          const float f = fminf(fmaxf((sv + 8.0f) * 4096.0f, 0.0f), 65535.0f);
          uint16_t* kbase = (uint16_t*)((char*)C + (size_t)rr * 4096 + 2048);
          kbase[col] = (uint16_t)(unsigned)f;
        } else if (EPI == 0) {
          C16[(size_t)rr * DD + col] = (_Float16)(v + bias[col]);
        } else {
          C[(size_t)rr * DD + col] = v + bias[col] + (float)resid16[(size_t)rr * DD + col];
        }
      }
    }
}

// =====================================================================
// Top-64 from u16 keys + masked softmax + sparse messages. One wave/row.
// Band: hi key>=cur+5 (provably in), out key<cur-4 (provably out).
// 2-product score error sigma ~0.4 cells; 4-cell margin = 3 cells score
// error (>=8 sigma) + 1 cell truncation. Candidates: exact fp32
// recompute from split Q,K; jax tie semantics (score desc, index asc).
// =====================================================================
__global__ __launch_bounds__(256, 4) void topk_softmax_msg(float* __restrict__ S,
                                                           const _Float16* __restrict__ V16,
                                                           const _Float16* __restrict__ Q1,
                                                           const _Float16* __restrict__ Q2,
                                                           const _Float16* __restrict__ K1,
                                                           const _Float16* __restrict__ K2,
                                                           const float* __restrict__ adj,
                                                           _Float16* __restrict__ M1) {
  const int tid = threadIdx.x;
  const int w = tid >> 6, lane = tid & 63;
  // XCD swizzle: batch = (t>>8)*8 + id%8 -> whole batch on one XCD
  const int id = blockIdx.x;            // 0..8191
  const int xcd = id & 7, t = id >> 3;  // t 0..1023
  const int b = (t >> 8) * 8 + xcd;     // batch 0..31
  const int row = b * NNODES + (t & 255) * 4 + w;
  const int m = row & (NNODES - 1);
  float* Srow = S + (size_t)row * NNODES;
  const uint16_t* krow = (const uint16_t*)((const char*)S + (size_t)row * 4096 + 2048);

  __shared__ float2 spair[4][KNB];  // (wgt, V16 row byte-offset bits)
  __shared__ int cidxs[4][32];
  __shared__ float cex[4][32];
  __shared__ int csel[4][32];

  if (lane < KNB) spair[w][lane] = make_float2(0.0f, __int_as_float(0));

  // load 16 keys: cols g*512 + lane*8 + e
  const uint4 u0 = *(const uint4*)(krow + lane * 8);
  const uint4 u1 = *(const uint4*)(krow + 512 + lane * 8);
  int k[16];
  {
    const unsigned uu[8] = {u0.x, u0.y, u0.z, u0.w, u1.x, u1.y, u1.z, u1.w};
#pragma unroll
    for (int q = 0; q < 8; ++q) {
      k[q * 2] = (int)(uu[q] & 0xffffu);
      k[q * 2 + 1] = (int)(uu[q] >> 16);
    }
  }
  // k[t] maps to col(t) = (t>>3)*512 + lane*8 + (t&7)

  float st[16];
#pragma unroll
  for (int t2 = 0; t2 < 16; ++t2) st[t2] = fmaf((float)k[t2] + 0.5f, KCELL, -8.0f);

  // radix-select 64th-largest key (16 bits)
  int cur = 0;
#pragma unroll 1
  for (int bit = 15; bit >= 0; --bit) {
    const int cand = cur | (1 << bit);
    int cnt = 0;
#pragma unroll
    for (int t2 = 0; t2 < 16; ++t2) cnt += (int)__popcll(__ballot(k[t2] >= cand));
    if (cnt >= KNB) cur = cand;
  }

  const int kHi = cur + 5;  // key >= kHi -> provably in top-64
  const int kLo = cur - 4;  // key <  kLo -> provably out

  const unsigned long long ltmask = (1ull << lane) - 1ull;
  unsigned hm = 0u, cm = 0u;
  int cpos[16];
  int nhi = 0, ncand = 0;
#pragma unroll
  for (int g = 0; g < 2; ++g) {
    bool hiv[8], cdv[8];
    unsigned long long mh[8], mc[8];
#pragma unroll
    for (int e = 0; e < 8; ++e) {
      const int t2 = g * 8 + e;
      hiv[e] = (k[t2] >= kHi);
      cdv[e] = (!hiv[e]) && (k[t2] >= kLo);
      mh[e] = __ballot(hiv[e]);
      mc[e] = __ballot(cdv[e]);
    }
    int below = 0, tot_h = 0, tot_c = 0;
#pragma unroll
    for (int e = 0; e < 8; ++e) {
      below += (int)__popcll(mc[e] & ltmask);
      tot_h += (int)__popcll(mh[e]);
      tot_c += (int)__popcll(mc[e]);
    }
    int own = 0;
#pragma unroll
    for (int e = 0; e < 8; ++e) {
      const int t2 = g * 8 + e;
      cpos[t2] = -1;
      if (hiv[e]) hm |= (1u << t2);
      if (cdv[e]) {
        cm |= (1u << t2);
        const int p = ncand + below + own;
        cpos[t2] = p;
        if (p < 32) cidxs[w][p] = g * 512 + lane * 8 + e;
        ++own;
      }
    }
    nhi += tot_h;
    ncand += tot_c;
  }
  const int need = KNB - nhi;  // >= 1; nhi+ncand >= 64

  unsigned selm;
  if (ncand == need) {
    selm = hm | cm;  // fast path
  } else {
    const int nc = (ncand <= 32) ? ncand : 32;
    const int nd = (need <= nc) ? need : nc;
    const size_t qoff = (size_t)row * DD + lane * 4;
    const half4 q1v = *(const half4*)(Q1 + qoff);
    const half4 q2v = *(const half4*)(Q2 + qoff);
    float qf[4];
#pragma unroll
    for (int e = 0; e < 4; ++e) qf[e] = (float)q1v[e] + (float)q2v[e];
    const float* adjrow = adj + (size_t)m * NNODES;
#pragma unroll 2
    for (int t2 = 0; t2 < nc; ++t2) {
      const int j = cidxs[w][t2];
      const size_t koff = ((size_t)b * NNODES + j) * DD + lane * 4;
      const half4 k1v = *(const half4*)(K1 + koff);
      const half4 k2v = *(const half4*)(K2 + koff);
      float part = 0.0f;
#pragma unroll
      for (int e = 0; e < 4; ++e) part = fmaf(qf[e], (float)k1v[e] + (float)k2v[e], part);
#pragma unroll
      for (int off = 32; off > 0; off >>= 1) part += __shfl_xor(part, off);
      if (lane == 0) cex[w][t2] = part * INV65536 + adjrow[j];
    }
    if (lane < nc) {
      const float et = cex[w][lane];
      int rank = 0;
      for (int u = 0; u < nc; ++u) {
        const float eu = cex[w][u];
        rank += (eu > et || (eu == et && u < lane)) ? 1 : 0;
      }
      csel[w][lane] = (rank < nd) ? 1 : 0;
    }
    selm = hm;
#pragma unroll
    for (int t2 = 0; t2 < 16; ++t2) {
      if (((cm >> t2) & 1u) && cpos[t2] >= 0 && cpos[t2] < 32 && csel[w][cpos[t2]]) selm |= (1u << t2);
    }
  }

  // softmax over selected (rmax over all; the max element is hi|cand)
  float rmax = st[0];
#pragma unroll
  for (int t2 = 1; t2 < 16; ++t2) rmax = fmaxf(rmax, st[t2]);
#pragma unroll
  for (int off = 32; off > 0; off >>= 1) rmax = fmaxf(rmax, __shfl_xor(rmax, off));

  float p[16];
  float sum = 0.0f;
#pragma unroll
  for (int t2 = 0; t2 < 16; ++t2) {
    p[t2] = __expf(st[t2] - rmax);
    if ((selm >> t2) & 1u) sum += p[t2];
  }
#pragma unroll
  for (int off = 32; off > 0; off >>= 1) sum += __shfl_xor(sum, off);
  const float inv = 1.0f / sum;

  // attn write (overwrites full 4KB row incl. key half) + ordered compaction
  int run = 0;
#pragma unroll
  for (int g = 0; g < 2; ++g) {
    bool sel8[8];
    unsigned long long ms[8];
#pragma unroll
    for (int e = 0; e < 8; ++e) {
      sel8[e] = (selm >> (g * 8 + e)) & 1u;
      ms[e] = __ballot(sel8[e]);
    }
    int below = 0, tot = 0;
#pragma unroll
    for (int e = 0; e < 8; ++e) {
      below += (int)__popcll(ms[e] & ltmask);
      tot += (int)__popcll(ms[e]);
    }
    float ow[8];
    int own = 0;
#pragma unroll
    for (int e = 0; e < 8; ++e) {
      const int t2 = g * 8 + e;
      const float aw = sel8[e] ? p[t2] * inv : 0.0f;
      ow[e] = aw;
      if (sel8[e]) {
        const int pos = run + below + own;
        // store V16 row byte-offset: col * DD * 2
        if (pos < KNB)
          spair[w][pos] = make_float2(aw, __int_as_float((g * 512 + lane * 8 + e) * (DD * 2)));
        ++own;
      }
    }
    float* dst = Srow + g * 512 + lane * 8;
    *(float4*)(dst) = make_float4(ow[0], ow[1], ow[2], ow[3]);
    *(float4*)(dst + 4) = make_float4(ow[4], ow[5], ow[6], ow[7]);
    run += tot;
  }

  // messages: lane owns output dims [lane*4, lane*4+4)
  float4 acc = {0.0f, 0.0f, 0.0f, 0.0f};
  const char* Vbase = (const char*)(V16 + (size_t)b * NNODES * DD) + lane * 8;
#pragma unroll 4
  for (int t2 = 0; t2 < KNB; ++t2) {
    const float2 pr = spair[w][t2];
    const int off = __float_as_int(pr.y);
    const half4 vv = *(const half4*)(Vbase + off);
    acc.x = fmaf(pr.x, (float)vv[0], acc.x);
    acc.y = fmaf(pr.x, (float)vv[1], acc.y);
    acc.z = fmaf(pr.x, (float)vv[2], acc.z);
    acc.w = fmaf(pr.x, (float)vv[3], acc.w);
  }
  // M stored as single fp16(64*m) -- downstream w1 runs 2-product
  half4 m1;
  m1[0] = (_Float16)(acc.x * 64.0f);
  m1[1] = (_Float16)(acc.y * 64.0f);
  m1[2] = (_Float16)(acc.z * 64.0f);
  m1[3] = (_Float16)(acc.w * 64.0f);
  *(half4*)(M1 + (size_t)row * DD + lane * 4) = m1;
}

// =====================================================================
// LayerNorm + ReLU: H16 fp16 -> single fp16(64*y). Wave per row, no LDS.
// =====================================================================
__global__ __launch_bounds__(256) void ln_relu(const _Float16* __restrict__ H16,
                                               const float* __restrict__ g,
                                               const float* __restrict__ bta,
                                               _Float16* __restrict__ H1) {
  const int tid = threadIdx.x;
  const int row = blockIdx.x * 4 + (tid >> 6);
  const int lane = tid & 63;
  const half4 hv = *(const half4*)(H16 + (size_t)row * DD + lane * 4);
  float h[4];
#pragma unroll
  for (int j = 0; j < 4; ++j) h[j] = (float)hv[j];

  float s = h[0] + h[1] + h[2] + h[3];
#pragma unroll
  for (int off = 32; off > 0; off >>= 1) s += __shfl_xor(s, off);
  const float mu = s * (1.0f / 256.0f);

  float d[4], sq = 0.0f;
#pragma unroll
  for (int j = 0; j < 4; ++j) {
    d[j] = h[j] - mu;
    sq += d[j] * d[j];
  }
#pragma unroll
  for (int off = 32; off > 0; off >>= 1) sq += __shfl_xor(sq, off);
  const float rstd = 1.0f / sqrtf(sq * (1.0f / 256.0f) + 1e-5f);

  const float4 gv = *(const float4*)(g + lane * 4);
  const float4 bv = *(const float4*)(bta + lane * 4);
  const float gg[4] = {gv.x, gv.y, gv.z, gv.w};
  const float bb[4] = {bv.x, bv.y, bv.z, bv.w};
  half4 o;
#pragma unroll
  for (int j = 0; j < 4; ++j) {
    const float y = fmaxf(d[j] * rstd * gg[j] + bb[j], 0.0f);
    o[j] = (_Float16)(y * 64.0f);
  }
  *(half4*)(H1 + (size_t)row * DD + lane * 4) = o;
}

// =====================================================================
// Host launch
// =====================================================================
extern "C" void kernel_launch(void* const* d_in, const int* in_sizes, int n_in,
                              void* d_out, int out_size, void* d_ws, size_t ws_size,
                              hipStream_t stream) {
  (void)in_sizes; (void)n_in; (void)out_size; (void)ws_size;
  const float* x   = (const float*)d_in[0];
  const float* wq  = (const float*)d_in[1];
  const float* bq  = (const float*)d_in[2];
  const float* wk  = (const float*)d_in[3];
  const float* bk  = (const float*)d_in[4];
  const float* wv  = (const float*)d_in[5];
  const float* bv  = (const float*)d_in[6];
  const float* adj = (const float*)d_in[7];
  const float* w1  = (const float*)d_in[8];
  const float* b1  = (const float*)d_in[9];
  const float* lng = (const float*)d_in[10];
  const float* lnb = (const float*)d_in[11];
  const float* w2  = (const float*)d_in[12];
  const float* b2  = (const float*)d_in[13];

  const size_t BND = (size_t)MTOT * DD;  // 8,388,608
  float* outp  = (float*)d_out;          // [MTOT][256] (written by final w2 gemm)
  float* attnp = outp + BND;             // [MTOT][1024] (X splits -> keys+attn)

  // X1/X2 live in the attn scratch region (dead before scores writes keys)
  _Float16* X1 = (_Float16*)attnp;
  _Float16* X2 = X1 + BND;

  _Float16* Q1 = (_Float16*)d_ws;   // ~85 MB total ws use (proven available)
  _Float16* Q2 = Q1 + BND;
  _Float16* K1 = Q2 + BND;
  _Float16* K2 = K1 + BND;
  _Float16* WT = K2 + BND;          // [5][2][65536]
  _Float16* V16 = WT + 5 * 131072;  // fp16 V (16.78 MB)

  _Float16* M1 = Q1;          // reuse after topk (wave reads own Q row first)
  _Float16* H16 = (_Float16*)K1;  // reuse K1 region after topk (16 MB)
  _Float16* H1 = Q1;          // reuse after w1 consumed M1

  const dim3 blk(256);

  prep_w<<<dim3(1280), blk, 0, stream>>>(wq, wk, wv, w1, w2, WT);
  prep_x<<<dim3(4096), blk, 0, stream>>>(x, X1, X2);
  gemm_qkv<<<dim3(1536), blk, 0, stream>>>(X1, X2, WT, bq, bk, bv, Q1, Q2, K1, K2, V16);
  gemm_split<2><<<dim3(8, 256), blk, 0, stream>>>(Q1, K1, K2, adj, nullptr, attnp, nullptr);
  topk_softmax_msg<<<dim3(MTOT / 4), blk, 0, stream>>>(attnp, V16, Q1, Q2, K1, K2, adj, M1);
  gemm_split<0><<<dim3(2, 256), blk, 0, stream>>>(M1, WT + 3 * 131072, WT + 3 * 131072 + 65536,
                                                  b1, nullptr, nullptr, H16);
  ln_relu<<<dim3(MTOT / 4), blk, 0, stream>>>(H16, lng, lnb, H1);
  gemm_split<1><<<dim3(2, 256), blk, 0, stream>>>(H1, WT + 4 * 131072, WT + 4 * 131072 + 65536,
                                                  b2, V16, outp, nullptr);
}